// Round 12
// baseline (209.840 us; speedup 1.0000x reference)
//
#include <hip/hip_runtime.h>

#define GG    300
#define NPTS  524288
#define CDEN  16
#define CAPP  48
#define ADIM  27
#define KTOT  144
#define TK    72      // LDS A row stride in bf16: cols 0..47 data, 48..63 zero, 64..71 pad
#define NBUCK     90000          // linear key = ycell*300 + zcell
#define NBUCK_PAD 90112          // 88 * 1024
#define NCHUNK    88
#define NBMAX 20                 // max buckets per wave on fast path
#define SLOTU 296                // u16 per slot: 6 rows * 48 + 8 pad (592B, 16B aligned)
#define NBLK  (NPTS/256)
#define NBLK64 (NPTS/64)
#define CHUNK64 (NBLK64/8)
#define TPBLK ((3*GG*GG + 255)/256)   // 1055

typedef unsigned int u32;
typedef unsigned short u16;
typedef __attribute__((ext_vector_type(8))) short s16x8;
typedef __attribute__((ext_vector_type(4))) float f32x4;

__device__ __forceinline__ u16 f2bf(float f){
  u32 u = __float_as_uint(f);
  u32 r = u + 0x7FFFu + ((u >> 16) & 1u);   // RNE
  return (u16)(r >> 16);
}
__device__ __forceinline__ float bflo(u32 u){ return __uint_as_float(u << 16); }
__device__ __forceinline__ float bfhi(u32 u){ return __uint_as_float(u & 0xFFFF0000u); }

struct IdxW { int i0, i1; float f; };
__device__ __forceinline__ IdxW idxw(float c){
  float x  = (c + 1.0f) * 0.5f * (float)(GG - 1);
  float x0 = floorf(x);
  IdxW r;
  r.f = x - x0;
  int i0 = (int)x0;
  i0 = i0 < 0 ? 0 : (i0 > GG-1 ? GG-1 : i0);
  int i1 = i0 + 1; if (i1 > GG-1) i1 = GG-1;
  r.i0 = i0; r.i1 = i1;
  return r;
}
__device__ __forceinline__ int cell_of(float c){
  float x = (c + 1.0f) * 0.5f * (float)(GG - 1);
  int i = (int)floorf(x);
  return i < 0 ? 0 : (i > GG-1 ? GG-1 : i);
}

// blend 8 channels from 6 row chunks -> ft[0..7]
__device__ __forceinline__ void blend8(uint4 u00, uint4 u01, uint4 u10, uint4 u11,
    uint4 ul0, uint4 ul1, float w00, float w01, float w10, float w11, float fd, float* ft)
{
  u32 a00[4]={u00.x,u00.y,u00.z,u00.w};
  u32 a01[4]={u01.x,u01.y,u01.z,u01.w};
  u32 a10[4]={u10.x,u10.y,u10.z,u10.w};
  u32 a11[4]={u11.x,u11.y,u11.z,u11.w};
  u32 al0[4]={ul0.x,ul0.y,ul0.z,ul0.w};
  u32 al1[4]={ul1.x,ul1.y,ul1.z,ul1.w};
  #pragma unroll
  for (int i = 0; i < 4; i++){
    float plo = w00*bflo(a00[i]) + w01*bflo(a01[i]) + w10*bflo(a10[i]) + w11*bflo(a11[i]);
    float phi = w00*bfhi(a00[i]) + w01*bfhi(a01[i]) + w10*bfhi(a10[i]) + w11*bfhi(a11[i]);
    float l0l = bflo(al0[i]), l1l = bflo(al1[i]);
    float l0h = bfhi(al0[i]), l1h = bfhi(al1[i]);
    ft[2*i+0] = plo * (l0l + fd*(l1l - l0l));
    ft[2*i+1] = phi * (l0h + fd*(l1h - l0h));
  }
}

__device__ __forceinline__ void sample8(const u16* P00, const u16* P01,
    const u16* P10, const u16* P11, const u16* L0, const u16* L1,
    float w00, float w01, float w10, float w11, float fd, float* ft)
{
  blend8(*(const uint4*)P00, *(const uint4*)P01, *(const uint4*)P10,
         *(const uint4*)P11, *(const uint4*)L0, *(const uint4*)L1,
         w00,w01,w10,w11, fd, ft);
}

// ---- fused prep: LDS-staged transposes + lines + B-frags + linear-key hist ----
__global__ __launch_bounds__(256) void prep_all(
    const float* __restrict__ dplane, const float* __restrict__ aplane,
    const float* __restrict__ dline,  const float* __restrict__ aline,
    const float* __restrict__ W,      const float* __restrict__ xyz,
    u16* __restrict__ dpt, u16* __restrict__ apt,
    u16* __restrict__ dlt, u16* __restrict__ alt,
    uint4* __restrict__ Bfr, u32* __restrict__ hist, u32* __restrict__ keys)
{
  __shared__ __align__(16) u16 T[256*52];   // 26.6 KB staging
  const int b = blockIdx.x;
  const int tid = threadIdx.x;
  if (b < TPBLK){
    const int cell0 = b*256;
    const int ncell = min(256, 3*GG*GG - cell0);
    const int cell  = cell0 + tid;
    if (tid < ncell){
      int p = cell/(GG*GG), rem = cell - p*(GG*GG);
      #pragma unroll
      for (int c = 0; c < CDEN; c++)
        T[tid*20 + c] = f2bf(dplane[((size_t)(p*CDEN+c))*(GG*GG) + rem]);
    }
    __syncthreads();
    uint2* dst = (uint2*)(dpt + (size_t)cell0*CDEN);
    const int nch = ncell*4;
    #pragma unroll
    for (int k = 0; k < 4; k++){
      int idx = k*256 + tid;
      if (idx < nch){
        int cl = idx >> 2, j = idx & 3;
        dst[idx] = *(const uint2*)(T + cl*20 + j*4);
      }
    }
  } else if (b < 2*TPBLK){
    const int cell0 = (b - TPBLK)*256;
    const int ncell = min(256, 3*GG*GG - cell0);
    const int cell  = cell0 + tid;
    if (tid < ncell){
      int p = cell/(GG*GG), rem = cell - p*(GG*GG);
      #pragma unroll
      for (int c = 0; c < CAPP; c++)
        T[tid*52 + c] = f2bf(aplane[((size_t)(p*CAPP+c))*(GG*GG) + rem]);
    }
    __syncthreads();
    uint2* dst = (uint2*)(apt + (size_t)cell0*CAPP);
    const int nch = ncell*12;
    #pragma unroll
    for (int k = 0; k < 12; k++){
      int idx = k*256 + tid;
      if (idx < nch){
        int cl = idx/12, j = idx - cl*12;
        dst[idx] = *(const uint2*)(T + cl*52 + j*4);
      }
    }
  } else if (b < 2*TPBLK + 4){
    int t = (b - 2*TPBLK)*256 + tid;
    if (t < 3*GG){
      int p = t / GG, d = t - p*GG;
      #pragma unroll
      for (int c = 0; c < CDEN; c++) dlt[t*CDEN + c] = f2bf(dline[(p*CDEN + c)*GG + d]);
      #pragma unroll
      for (int c = 0; c < CAPP; c++) alt[t*CAPP + c] = f2bf(aline[(p*CAPP + c)*GG + d]);
    }
  } else if (b < 2*TPBLK + 7){
    int t = (b - (2*TPBLK + 4))*256 + tid;
    if (t < 3*2*2*64){
      int lane = t & 63;
      int st = (t >> 6) & 1;
      int nt = (t >> 7) & 1;
      int p  = t >> 8;
      int a  = nt*16 + (lane & 15);
      int kb = st*32 + ((lane >> 4) * 8);
      u32 d[4];
      #pragma unroll
      for (int j2 = 0; j2 < 4; j2++){
        int k0 = kb + 2*j2, k1 = k0 + 1;
        u32 lo = (a < ADIM && k0 < 48) ? (u32)f2bf(W[a*KTOT + p*48 + k0]) : 0u;
        u32 hi = (a < ADIM && k1 < 48) ? (u32)f2bf(W[a*KTOT + p*48 + k1]) : 0u;
        d[j2] = lo | (hi << 16);
      }
      Bfr[t] = make_uint4(d[0], d[1], d[2], d[3]);
    }
  } else {
    int n = (b - (2*TPBLK + 7))*256 + tid;
    float Y = xyz[3*n+1], Z = xyz[3*n+2];
    u32 key = (u32)cell_of(Y)*300u + (u32)cell_of(Z);
    keys[n] = key;
    atomicAdd(&hist[key], 1u);
  }
}

// ---- 2-level scan over 90112 padded buckets ----
__global__ __launch_bounds__(1024) void scan1(const u32* __restrict__ hist,
                                              u32* __restrict__ offs,
                                              u32* __restrict__ csum){
  __shared__ u32 part[1024];
  const int t = threadIdx.x;
  const int i = blockIdx.x*1024 + t;
  u32 v = hist[i];
  part[t] = v;
  __syncthreads();
  for (int off = 1; off < 1024; off <<= 1){
    u32 x = (t >= off) ? part[t - off] : 0;
    __syncthreads();
    part[t] += x;
    __syncthreads();
  }
  offs[i] = part[t] - v;
  if (t == 1023) csum[blockIdx.x] = part[t];
}

__global__ __launch_bounds__(256) void scan2(const u32* __restrict__ csum,
                                             u32* __restrict__ cbase){
  __shared__ u32 part[256];
  const int t = threadIdx.x;
  u32 v = (t < NCHUNK) ? csum[t] : 0;
  part[t] = v;
  __syncthreads();
  for (int off = 1; off < 256; off <<= 1){
    u32 x = (t >= off) ? part[t - off] : 0;
    __syncthreads();
    part[t] += x;
    __syncthreads();
  }
  if (t < NCHUNK) cbase[t] = part[t] - v;
}

__global__ __launch_bounds__(256) void scatter_pts(const float* __restrict__ xyz,
                                                   const u32* __restrict__ keys,
                                                   u32* __restrict__ offs,
                                                   const u32* __restrict__ cbase,
                                                   float4* __restrict__ xyzq){
  int n = blockIdx.x*256 + threadIdx.x;
  u32 key = keys[n];
  u32 pos = cbase[key >> 10] + atomicAdd(&offs[key], 1u);
  float4 q;
  q.x = xyz[3*n+0]; q.y = xyz[3*n+1]; q.z = xyz[3*n+2];
  q.w = __int_as_float(n);
  xyzq[pos] = q;
}

// ---- main: fused sampling + per-wave MFMA GEMM. ONE WAVE PER BLOCK ----
// R12: app-row dedupe for planes 0/1. Wave's 64 sorted points span a
// CONTIGUOUS bucket range (linear key) -> slot = key - firstb, no ballot.
// Cooperative load of nb x 6 app rows (96B each) into LDS (~7 coalesced
// instrs vs 36 per-point gathers), per-point app sampling reads LDS
// (ds_read ~12cy vs global gather ~62cy). Fallback (wave-uniform) to the
// proven global path when nb > NBMAX. Density + plane2 unchanged.
// DO NOT add the 2nd launch_bounds arg (R4: spill; R8: miscompute).
template<bool SORTED>
__global__ __launch_bounds__(64) void sample_mfma(
    const float4* __restrict__ xyzq,
    const float* __restrict__ xyz,
    const u16*  __restrict__ dpt,
    const u16*  __restrict__ apt,
    const u16*  __restrict__ dlt,
    const u16*  __restrict__ alt,
    const uint4* __restrict__ Bfr,
    float* __restrict__ outv)
{
  __shared__ __align__(16) u16 Asm[64*TK];        // 9216 B
  __shared__ __align__(16) u16 Crow[NBMAX*SLOTU]; // 11840 B app-row cache
  const int lane = threadIdx.x;
  int bid = blockIdx.x;
  if (SORTED) bid = (bid & 7)*CHUNK64 + (bid >> 3);
  const int n = bid*64 + lane;

  float X, Y, Z; int pn;
  if (SORTED){
    float4 q = xyzq[n];
    X = q.x; Y = q.y; Z = q.z; pn = __float_as_int(q.w);
  } else {
    X = xyz[3*n+0]; Y = xyz[3*n+1]; Z = xyz[3*n+2]; pn = n;
  }

  // bucket range of this wave (contiguous since sorted by linear key)
  u32 firstb = 0; int slot = 0; bool fast = false;
  if (SORTED){
    u32 mykey = (u32)cell_of(Y)*300u + (u32)cell_of(Z);
    firstb = __shfl(mykey, 0);
    u32 lastb = __shfl(mykey, 63);
    int nbv = (int)(lastb - firstb) + 1;
    fast = (nbv <= NBMAX);
    slot = (int)(mykey - firstb);
    if (fast){} // nb used below via nbw
  }
  int nbw = SORTED ? ((int)(__shfl((u32)((u32)cell_of(Y)*300u + (u32)cell_of(Z)), 63) - firstb) + 1) : 0;

  u16* Arow = Asm + lane*TK;
  const u16* Awave = Asm;

  float sigma = 0.f;
  f32x4 acc[4][2];
  #pragma unroll
  for (int t = 0; t < 4; t++){
    acc[t][0] = (f32x4){0.f,0.f,0.f,0.f};
    acc[t][1] = (f32x4){0.f,0.f,0.f,0.f};
  }

  uint4 z4 = make_uint4(0,0,0,0);
  *(uint4*)(Arow + 48) = z4;
  *(uint4*)(Arow + 56) = z4;

  #pragma unroll 1
  for (int p = 0; p < 3; p++){
    const float dc = (p==0) ? Z : ((p==1) ? Y : X);
    const float hc = (p==0) ? Y : Z;

    uint4 b00 = Bfr[(p*4 + 0)*64 + lane];
    uint4 b01 = Bfr[(p*4 + 1)*64 + lane];
    uint4 b10 = Bfr[(p*4 + 2)*64 + lane];
    uint4 b11 = Bfr[(p*4 + 3)*64 + lane];

    IdxW D = idxw(dc), H = idxw(hc);
    const float fd = D.f, fh = H.f;
    const float w00 = (1.f-fd)*(1.f-fh), w01 = (1.f-fd)*fh;
    const float w10 = fd*(1.f-fh),       w11 = fd*fh;

    { // density -> sigma (per-point global, cheap: 12 instrs/plane)
      const u16* P00 = dpt + ((p*GG+D.i0)*GG+H.i0)*CDEN;
      const u16* P01 = dpt + ((p*GG+D.i0)*GG+H.i1)*CDEN;
      const u16* P10 = dpt + ((p*GG+D.i1)*GG+H.i0)*CDEN;
      const u16* P11 = dpt + ((p*GG+D.i1)*GG+H.i1)*CDEN;
      const u16* L0  = dlt + (p*GG+D.i0)*CDEN;
      const u16* L1  = dlt + (p*GG+D.i1)*CDEN;
      #pragma unroll
      for (int g = 0; g < 2; g++){
        float ft[8];
        sample8(P00+g*8, P01+g*8, P10+g*8, P11+g*8, L0+g*8, L1+g*8,
                w00,w01,w10,w11, fd, ft);
        sigma += ((ft[0]+ft[1])+(ft[2]+ft[3])) + ((ft[4]+ft[5])+(ft[6]+ft[7]));
      }
    }

    if (SORTED && fast && p < 2){
      // cooperative app-row load: nb slots x 6 rows x 48 u16 into Crow
      int nch = nbw*36;   // 16B chunks
      for (int i = lane; i < nch; i += 64){
        int s   = i/36, c = i - s*36;
        int row = c/6,  off = c - row*6;
        u32 bk = firstb + (u32)s;
        int by = (int)(bk/300u), bz = (int)(bk - 300u*(u32)by);
        int d0 = (p==0) ? bz : by;
        int h0 = (p==0) ? by : bz;
        int d1 = d0+1 > GG-1 ? GG-1 : d0+1;
        int h1 = h0+1 > GG-1 ? GG-1 : h0+1;
        const u16* src;
        if (row < 4){
          int di = (row>>1) ? d1 : d0;
          int hi = (row&1)  ? h1 : h0;
          src = apt + ((size_t)(p*GG + di)*GG + hi)*CAPP + off*8;
        } else {
          int di = (row==5) ? d1 : d0;
          src = alt + (size_t)(p*GG + di)*CAPP + off*8;
        }
        *(uint4*)(Crow + s*SLOTU + c*8) = *(const uint4*)src;
      }
      asm volatile("" ::: "memory");
      // per-point app sampling from LDS
      const u16* S = Crow + slot*SLOTU;
      #pragma unroll 2
      for (int g = 0; g < 6; g++){
        float ft[8];
        blend8(*(const uint4*)(S + 0*48 + g*8), *(const uint4*)(S + 1*48 + g*8),
               *(const uint4*)(S + 2*48 + g*8), *(const uint4*)(S + 3*48 + g*8),
               *(const uint4*)(S + 4*48 + g*8), *(const uint4*)(S + 5*48 + g*8),
               w00,w01,w10,w11, fd, ft);
        uint4 d;
        d.x = (u32)f2bf(ft[0]) | ((u32)f2bf(ft[1]) << 16);
        d.y = (u32)f2bf(ft[2]) | ((u32)f2bf(ft[3]) << 16);
        d.z = (u32)f2bf(ft[4]) | ((u32)f2bf(ft[5]) << 16);
        d.w = (u32)f2bf(ft[6]) | ((u32)f2bf(ft[7]) << 16);
        *(uint4*)(Arow + g*8) = d;
      }
      asm volatile("" ::: "memory");  // Crow reads done before next plane's writes
    } else {
      // per-point global app path (fallback / plane2)
      const u16* P00 = apt + ((p*GG+D.i0)*GG+H.i0)*CAPP;
      const u16* P01 = apt + ((p*GG+D.i0)*GG+H.i1)*CAPP;
      const u16* P10 = apt + ((p*GG+D.i1)*GG+H.i0)*CAPP;
      const u16* P11 = apt + ((p*GG+D.i1)*GG+H.i1)*CAPP;
      const u16* L0  = alt + (p*GG+D.i0)*CAPP;
      const u16* L1  = alt + (p*GG+D.i1)*CAPP;
      #pragma unroll 2
      for (int g = 0; g < 6; g++){
        float ft[8];
        sample8(P00+g*8, P01+g*8, P10+g*8, P11+g*8, L0+g*8, L1+g*8,
                w00,w01,w10,w11, fd, ft);
        uint4 d;
        d.x = (u32)f2bf(ft[0]) | ((u32)f2bf(ft[1]) << 16);
        d.y = (u32)f2bf(ft[2]) | ((u32)f2bf(ft[3]) << 16);
        d.z = (u32)f2bf(ft[4]) | ((u32)f2bf(ft[5]) << 16);
        d.w = (u32)f2bf(ft[6]) | ((u32)f2bf(ft[7]) << 16);
        *(uint4*)(Arow + g*8) = d;
      }
    }

    asm volatile("" ::: "memory");   // A-tile visible before MFMA reads

    #pragma unroll
    for (int t = 0; t < 4; t++){
      const u16* ab = Awave + (t*16 + (lane & 15))*TK + ((lane >> 4) * 8);
      s16x8 a0 = __builtin_bit_cast(s16x8, *(const uint4*)ab);
      s16x8 a1 = __builtin_bit_cast(s16x8, *(const uint4*)(ab + 32));
      acc[t][0] = __builtin_amdgcn_mfma_f32_16x16x32_bf16(a0, __builtin_bit_cast(s16x8,b00), acc[t][0], 0,0,0);
      acc[t][0] = __builtin_amdgcn_mfma_f32_16x16x32_bf16(a1, __builtin_bit_cast(s16x8,b01), acc[t][0], 0,0,0);
      acc[t][1] = __builtin_amdgcn_mfma_f32_16x16x32_bf16(a0, __builtin_bit_cast(s16x8,b10), acc[t][1], 0,0,0);
      acc[t][1] = __builtin_amdgcn_mfma_f32_16x16x32_bf16(a1, __builtin_bit_cast(s16x8,b11), acc[t][1], 0,0,0);
    }
    asm volatile("" ::: "memory");   // MFMA A-reads done before next plane's writes
  }

  outv[pn] = sigma;

  float* ao = outv + NPTS;
  #pragma unroll
  for (int t = 0; t < 4; t++){
    #pragma unroll
    for (int nt = 0; nt < 2; nt++){
      int a = nt*16 + (lane & 15);
      #pragma unroll
      for (int r = 0; r < 4; r++){
        int src = t*16 + (lane >> 4)*4 + r;
        int pr = __shfl(pn, src);
        if (a < ADIM)
          ao[(size_t)pr*ADIM + a] = acc[t][nt][r];
      }
    }
  }
}

// ---- fallback: direct fp32 sampling ----
__global__ void sample_naive(const float* __restrict__ xyz,
    const float* __restrict__ dp, const float* __restrict__ dl,
    const float* __restrict__ ap, const float* __restrict__ al,
    const float* __restrict__ W,  float* __restrict__ outv)
{
  int n = blockIdx.x*blockDim.x + threadIdx.x;
  if (n >= NPTS) return;
  float X = xyz[3*n], Y = xyz[3*n+1], Z = xyz[3*n+2];
  float dco[3] = {Z, Y, X};
  float hco[3] = {Y, Z, Z};
  float sigma = 0.f, acc[ADIM];
  for (int a = 0; a < ADIM; a++) acc[a] = 0.f;
  for (int p = 0; p < 3; p++){
    IdxW D = idxw(dco[p]), H = idxw(hco[p]);
    float fd = D.f, fh = H.f;
    float w00=(1.f-fd)*(1.f-fh), w01=(1.f-fd)*fh, w10=fd*(1.f-fh), w11=fd*fh;
    for (int c = 0; c < CDEN; c++){
      const float* pl = dp + (size_t)(p*CDEN + c)*GG*GG;
      float pv = w00*pl[D.i0*GG+H.i0] + w01*pl[D.i0*GG+H.i1]
               + w10*pl[D.i1*GG+H.i0] + w11*pl[D.i1*GG+H.i1];
      const float* ll = dl + (p*CDEN + c)*GG;
      sigma += pv * (ll[D.i0] + fd*(ll[D.i1] - ll[D.i0]));
    }
    for (int c = 0; c < CAPP; c++){
      const float* pl = ap + (size_t)(p*CAPP + c)*GG*GG;
      float pv = w00*pl[D.i0*GG+H.i0] + w01*pl[D.i0*GG+H.i1]
               + w10*pl[D.i1*GG+H.i0] + w11*pl[D.i1*GG+H.i1];
      const float* ll = al + (p*CAPP + c)*GG;
      float ft = pv * (ll[D.i0] + fd*(ll[D.i1] - ll[D.i0]));
      int k = p*CAPP + c;
      for (int a = 0; a < ADIM; a++) acc[a] = fmaf(ft, W[a*KTOT + k], acc[a]);
    }
  }
  outv[n] = sigma;
  for (int a = 0; a < ADIM; a++) outv[NPTS + (size_t)n*ADIM + a] = acc[a];
}

extern "C" void kernel_launch(void* const* d_in, const int* in_sizes, int n_in,
                              void* d_out, int out_size, void* d_ws, size_t ws_size,
                              hipStream_t stream){
  const float* xyz    = (const float*)d_in[0];
  const float* dplane = (const float*)d_in[1];
  const float* dline  = (const float*)d_in[2];
  const float* aplane = (const float*)d_in[3];
  const float* aline  = (const float*)d_in[4];
  const float* W      = (const float*)d_in[5];
  float* outv = (float*)d_out;

  const size_t sz_dpt  = (size_t)3*GG*GG*CDEN*2;
  const size_t sz_apt  = (size_t)3*GG*GG*CAPP*2;
  const size_t sz_dlt  = (size_t)3*GG*CDEN*2;
  const size_t sz_alt  = (size_t)3*GG*CAPP*2;
  const size_t sz_bfr  = (size_t)3*2*2*64*16;
  const size_t sz_hist = (size_t)NBUCK_PAD*4;
  const size_t sz_offs = (size_t)NBUCK_PAD*4;
  const size_t sz_csum = (size_t)NCHUNK*4;
  const size_t sz_cbase= (size_t)NCHUNK*4;
  const size_t sz_keys = (size_t)NPTS*4;
  const size_t sz_xyzq = (size_t)NPTS*16;

  const size_t off_apt  = sz_dpt;
  const size_t off_dlt  = off_apt + sz_apt;
  const size_t off_alt  = off_dlt + sz_dlt;
  const size_t off_bfr  = off_alt + sz_alt;
  const size_t off_hist = off_bfr + sz_bfr;
  const size_t off_offs = off_hist + sz_hist;
  const size_t off_csum = off_offs + sz_offs;
  const size_t off_cbase= off_csum + sz_csum;
  const size_t off_keys = off_cbase + sz_cbase;
  const size_t off_xyzq = off_keys + sz_keys;
  const size_t need_tab  = off_hist;
  const size_t need_full = off_xyzq + sz_xyzq;

  if (ws_size < need_tab){
    sample_naive<<<(NPTS+255)/256, 256, 0, stream>>>(xyz, dplane, dline, aplane, aline, W, outv);
    return;
  }

  u16*   dpt = (u16*)((char*)d_ws);
  u16*   apt = (u16*)((char*)d_ws + off_apt);
  u16*   dlt = (u16*)((char*)d_ws + off_dlt);
  u16*   alt = (u16*)((char*)d_ws + off_alt);
  uint4* bfr = (uint4*)((char*)d_ws + off_bfr);

  if (ws_size < need_full){
    prep_all<<<2*TPBLK + 7, 256, 0, stream>>>(dplane, aplane, dline, aline, W, xyz,
                                              dpt, apt, dlt, alt, bfr, nullptr, nullptr);
    sample_mfma<false><<<NBLK64, 64, 0, stream>>>(nullptr, xyz, dpt, apt, dlt, alt, bfr, outv);
    return;
  }

  u32*    hist = (u32*)((char*)d_ws + off_hist);
  u32*    offs = (u32*)((char*)d_ws + off_offs);
  u32*    csum = (u32*)((char*)d_ws + off_csum);
  u32*    cbase= (u32*)((char*)d_ws + off_cbase);
  u32*    keys = (u32*)((char*)d_ws + off_keys);
  float4* xyzq = (float4*)((char*)d_ws + off_xyzq);

  hipMemsetAsync(hist, 0, sz_hist, stream);
  prep_all<<<2*TPBLK + 7 + NBLK, 256, 0, stream>>>(dplane, aplane, dline, aline, W, xyz,
                                                   dpt, apt, dlt, alt, bfr, hist, keys);
  scan1<<<NCHUNK, 1024, 0, stream>>>(hist, offs, csum);
  scan2<<<1, 256, 0, stream>>>(csum, cbase);
  scatter_pts<<<NBLK, 256, 0, stream>>>(xyz, keys, offs, cbase, xyzq);
  sample_mfma<true><<<NBLK64, 64, 0, stream>>>(xyzq, nullptr, dpt, apt, dlt, alt, bfr, outv);
}

// Round 13
// 202.011 us; speedup vs baseline: 1.0388x; 1.0388x over previous
//
#include <hip/hip_runtime.h>

#define GG    300
#define NPTS  524288
#define CDEN  16
#define CAPP  48
#define ADIM  27
#define KTOT  144
#define TK    72      // LDS A row stride in bf16: cols 0..47 data, 48..63 zero, 64..71 pad
#define NBUCK     90000          // linear key = ycell*300 + zcell
#define NBUCK_PAD 90112          // 88 * 1024
#define NCHUNK    88
#define NBLK  (NPTS/256)
#define NBLK64 (NPTS/64)
#define CHUNK64 (NBLK64/8)
#define TPBLK ((3*GG*GG + 255)/256)   // 1055

typedef unsigned int u32;
typedef unsigned short u16;
typedef __attribute__((ext_vector_type(8))) short s16x8;
typedef __attribute__((ext_vector_type(4))) float f32x4;

__device__ __forceinline__ u16 f2bf(float f){
  u32 u = __float_as_uint(f);
  u32 r = u + 0x7FFFu + ((u >> 16) & 1u);   // RNE
  return (u16)(r >> 16);
}
__device__ __forceinline__ float bflo(u32 u){ return __uint_as_float(u << 16); }
__device__ __forceinline__ float bfhi(u32 u){ return __uint_as_float(u & 0xFFFF0000u); }

struct IdxW { int i0, i1; float f; };
__device__ __forceinline__ IdxW idxw(float c){
  float x  = (c + 1.0f) * 0.5f * (float)(GG - 1);
  float x0 = floorf(x);
  IdxW r;
  r.f = x - x0;
  int i0 = (int)x0;
  i0 = i0 < 0 ? 0 : (i0 > GG-1 ? GG-1 : i0);
  int i1 = i0 + 1; if (i1 > GG-1) i1 = GG-1;
  r.i0 = i0; r.i1 = i1;
  return r;
}
__device__ __forceinline__ int cell_of(float c){
  float x = (c + 1.0f) * 0.5f * (float)(GG - 1);
  int i = (int)floorf(x);
  return i < 0 ? 0 : (i > GG-1 ? GG-1 : i);
}

// sample 8 channels: bilinear plane * linear line -> ft[0..7]
__device__ __forceinline__ void sample8(const u16* P00, const u16* P01,
    const u16* P10, const u16* P11, const u16* L0, const u16* L1,
    float w00, float w01, float w10, float w11, float fd, float* ft)
{
  uint4 u00 = *(const uint4*)P00;
  uint4 u01 = *(const uint4*)P01;
  uint4 u10 = *(const uint4*)P10;
  uint4 u11 = *(const uint4*)P11;
  uint4 ul0 = *(const uint4*)L0;
  uint4 ul1 = *(const uint4*)L1;
  u32 a00[4]={u00.x,u00.y,u00.z,u00.w};
  u32 a01[4]={u01.x,u01.y,u01.z,u01.w};
  u32 a10[4]={u10.x,u10.y,u10.z,u10.w};
  u32 a11[4]={u11.x,u11.y,u11.z,u11.w};
  u32 al0[4]={ul0.x,ul0.y,ul0.z,ul0.w};
  u32 al1[4]={ul1.x,ul1.y,ul1.z,ul1.w};
  #pragma unroll
  for (int i = 0; i < 4; i++){
    float plo = w00*bflo(a00[i]) + w01*bflo(a01[i]) + w10*bflo(a10[i]) + w11*bflo(a11[i]);
    float phi = w00*bfhi(a00[i]) + w01*bfhi(a01[i]) + w10*bfhi(a10[i]) + w11*bfhi(a11[i]);
    float l0l = bflo(al0[i]), l1l = bflo(al1[i]);
    float l0h = bfhi(al0[i]), l1h = bfhi(al1[i]);
    ft[2*i+0] = plo * (l0l + fd*(l1l - l0l));
    ft[2*i+1] = phi * (l0h + fd*(l1h - l0h));
  }
}

// ---- fused prep: LDS-staged transposes + lines + B-frags + linear-key hist ----
__global__ __launch_bounds__(256) void prep_all(
    const float* __restrict__ dplane, const float* __restrict__ aplane,
    const float* __restrict__ dline,  const float* __restrict__ aline,
    const float* __restrict__ W,      const float* __restrict__ xyz,
    u16* __restrict__ dpt, u16* __restrict__ apt,
    u16* __restrict__ dlt, u16* __restrict__ alt,
    uint4* __restrict__ Bfr, u32* __restrict__ hist, u32* __restrict__ keys)
{
  __shared__ __align__(16) u16 T[256*52];   // 26.6 KB staging
  const int b = blockIdx.x;
  const int tid = threadIdx.x;
  if (b < TPBLK){
    const int cell0 = b*256;
    const int ncell = min(256, 3*GG*GG - cell0);
    const int cell  = cell0 + tid;
    if (tid < ncell){
      int p = cell/(GG*GG), rem = cell - p*(GG*GG);
      #pragma unroll
      for (int c = 0; c < CDEN; c++)
        T[tid*20 + c] = f2bf(dplane[((size_t)(p*CDEN+c))*(GG*GG) + rem]);
    }
    __syncthreads();
    uint2* dst = (uint2*)(dpt + (size_t)cell0*CDEN);
    const int nch = ncell*4;
    #pragma unroll
    for (int k = 0; k < 4; k++){
      int idx = k*256 + tid;
      if (idx < nch){
        int cl = idx >> 2, j = idx & 3;
        dst[idx] = *(const uint2*)(T + cl*20 + j*4);
      }
    }
  } else if (b < 2*TPBLK){
    const int cell0 = (b - TPBLK)*256;
    const int ncell = min(256, 3*GG*GG - cell0);
    const int cell  = cell0 + tid;
    if (tid < ncell){
      int p = cell/(GG*GG), rem = cell - p*(GG*GG);
      #pragma unroll
      for (int c = 0; c < CAPP; c++)
        T[tid*52 + c] = f2bf(aplane[((size_t)(p*CAPP+c))*(GG*GG) + rem]);
    }
    __syncthreads();
    uint2* dst = (uint2*)(apt + (size_t)cell0*CAPP);
    const int nch = ncell*12;
    #pragma unroll
    for (int k = 0; k < 12; k++){
      int idx = k*256 + tid;
      if (idx < nch){
        int cl = idx/12, j = idx - cl*12;
        dst[idx] = *(const uint2*)(T + cl*52 + j*4);
      }
    }
  } else if (b < 2*TPBLK + 4){
    int t = (b - 2*TPBLK)*256 + tid;
    if (t < 3*GG){
      int p = t / GG, d = t - p*GG;
      #pragma unroll
      for (int c = 0; c < CDEN; c++) dlt[t*CDEN + c] = f2bf(dline[(p*CDEN + c)*GG + d]);
      #pragma unroll
      for (int c = 0; c < CAPP; c++) alt[t*CAPP + c] = f2bf(aline[(p*CAPP + c)*GG + d]);
    }
  } else if (b < 2*TPBLK + 7){
    int t = (b - (2*TPBLK + 4))*256 + tid;
    if (t < 3*2*2*64){
      int lane = t & 63;
      int st = (t >> 6) & 1;
      int nt = (t >> 7) & 1;
      int p  = t >> 8;
      int a  = nt*16 + (lane & 15);
      int kb = st*32 + ((lane >> 4) * 8);
      u32 d[4];
      #pragma unroll
      for (int j2 = 0; j2 < 4; j2++){
        int k0 = kb + 2*j2, k1 = k0 + 1;
        u32 lo = (a < ADIM && k0 < 48) ? (u32)f2bf(W[a*KTOT + p*48 + k0]) : 0u;
        u32 hi = (a < ADIM && k1 < 48) ? (u32)f2bf(W[a*KTOT + p*48 + k1]) : 0u;
        d[j2] = lo | (hi << 16);
      }
      Bfr[t] = make_uint4(d[0], d[1], d[2], d[3]);
    }
  } else {
    int n = (b - (2*TPBLK + 7))*256 + tid;
    float Y = xyz[3*n+1], Z = xyz[3*n+2];
    u32 key = (u32)cell_of(Y)*300u + (u32)cell_of(Z);
    keys[n] = key;
    atomicAdd(&hist[key], 1u);
  }
}

// ---- scan1: per-1024-chunk exclusive scan (88 blocks, coalesced) ----
__global__ __launch_bounds__(1024) void scan1(const u32* __restrict__ hist,
                                              u32* __restrict__ offs,
                                              u32* __restrict__ csum){
  __shared__ u32 part[1024];
  const int t = threadIdx.x;
  const int i = blockIdx.x*1024 + t;
  u32 v = hist[i];
  part[t] = v;
  __syncthreads();
  for (int off = 1; off < 1024; off <<= 1){
    u32 x = (t >= off) ? part[t - off] : 0;
    __syncthreads();
    part[t] += x;
    __syncthreads();
  }
  offs[i] = part[t] - v;
  if (t == 1023) csum[blockIdx.x] = part[t];
}

// ---- scatter with inline chunk-base scan (scan2 folded in) ----
__global__ __launch_bounds__(256) void scatter_pts(const float* __restrict__ xyz,
                                                   const u32* __restrict__ keys,
                                                   u32* __restrict__ offs,
                                                   const u32* __restrict__ csum,
                                                   float4* __restrict__ xyzq){
  __shared__ u32 part[128];
  __shared__ u32 cb[NCHUNK];
  const int t = threadIdx.x;
  u32 cv = 0;
  if (t < 128){
    cv = (t < NCHUNK) ? csum[t] : 0;
    part[t] = cv;
  }
  __syncthreads();
  for (int off = 1; off < 128; off <<= 1){
    u32 x = 0;
    if (t < 128 && t >= off) x = part[t - off];
    __syncthreads();
    if (t < 128) part[t] += x;
    __syncthreads();
  }
  if (t < NCHUNK) cb[t] = part[t] - cv;   // exclusive chunk base
  __syncthreads();

  int n = blockIdx.x*256 + t;
  u32 key = keys[n];
  u32 pos = cb[key >> 10] + atomicAdd(&offs[key], 1u);
  float4 q;
  q.x = xyz[3*n+0]; q.y = xyz[3*n+1]; q.z = xyz[3*n+2];
  q.w = __int_as_float(n);
  xyzq[pos] = q;
}

// ---- main: fused sampling + per-wave MFMA GEMM. ONE WAVE PER BLOCK ----
// R11-proven body (137us): plain __launch_bounds__(64), fences asm(""),
// unroll1 planes / unroll2 app, Asm-only LDS (9216B), XCD-chunked swizzle.
// DO NOT add the 2nd launch_bounds arg (R4: spill; R8: miscompute).
// Kernel is at its L1/TA address-throughput roofline: 144 gather instrs/pt
// = 295K lane-addrs/CU @ ~1/cy = 123us model vs ~137 measured. R12's LDS
// dedupe regressed (+16us): moving reads between pipes doesn't beat it.
template<bool SORTED>
__global__ __launch_bounds__(64) void sample_mfma(
    const float4* __restrict__ xyzq,
    const float* __restrict__ xyz,
    const u16*  __restrict__ dpt,
    const u16*  __restrict__ apt,
    const u16*  __restrict__ dlt,
    const u16*  __restrict__ alt,
    const uint4* __restrict__ Bfr,
    float* __restrict__ outv)
{
  __shared__ __align__(16) u16 Asm[64*TK];   // 9216 B, wave-private
  const int lane = threadIdx.x;
  int bid = blockIdx.x;
  if (SORTED) bid = (bid & 7)*CHUNK64 + (bid >> 3);
  const int n = bid*64 + lane;

  float X, Y, Z; int pn;
  if (SORTED){
    float4 q = xyzq[n];
    X = q.x; Y = q.y; Z = q.z; pn = __float_as_int(q.w);
  } else {
    X = xyz[3*n+0]; Y = xyz[3*n+1]; Z = xyz[3*n+2]; pn = n;
  }

  u16* Arow = Asm + lane*TK;
  const u16* Awave = Asm;

  float sigma = 0.f;
  f32x4 acc[4][2];
  #pragma unroll
  for (int t = 0; t < 4; t++){
    acc[t][0] = (f32x4){0.f,0.f,0.f,0.f};
    acc[t][1] = (f32x4){0.f,0.f,0.f,0.f};
  }

  uint4 z4 = make_uint4(0,0,0,0);
  *(uint4*)(Arow + 48) = z4;
  *(uint4*)(Arow + 56) = z4;

  #pragma unroll 1
  for (int p = 0; p < 3; p++){
    const float dc = (p==0) ? Z : ((p==1) ? Y : X);
    const float hc = (p==0) ? Y : Z;

    uint4 b00 = Bfr[(p*4 + 0)*64 + lane];
    uint4 b01 = Bfr[(p*4 + 1)*64 + lane];
    uint4 b10 = Bfr[(p*4 + 2)*64 + lane];
    uint4 b11 = Bfr[(p*4 + 3)*64 + lane];

    IdxW D = idxw(dc), H = idxw(hc);
    const float fd = D.f, fh = H.f;
    const float w00 = (1.f-fd)*(1.f-fh), w01 = (1.f-fd)*fh;
    const float w10 = fd*(1.f-fh),       w11 = fd*fh;

    { // density -> sigma
      const u16* P00 = dpt + ((p*GG+D.i0)*GG+H.i0)*CDEN;
      const u16* P01 = dpt + ((p*GG+D.i0)*GG+H.i1)*CDEN;
      const u16* P10 = dpt + ((p*GG+D.i1)*GG+H.i0)*CDEN;
      const u16* P11 = dpt + ((p*GG+D.i1)*GG+H.i1)*CDEN;
      const u16* L0  = dlt + (p*GG+D.i0)*CDEN;
      const u16* L1  = dlt + (p*GG+D.i1)*CDEN;
      #pragma unroll
      for (int g = 0; g < 2; g++){
        float ft[8];
        sample8(P00+g*8, P01+g*8, P10+g*8, P11+g*8, L0+g*8, L1+g*8,
                w00,w01,w10,w11, fd, ft);
        sigma += ((ft[0]+ft[1])+(ft[2]+ft[3])) + ((ft[4]+ft[5])+(ft[6]+ft[7]));
      }
    }

    { // app feats -> LDS A tile (unroll 2: bounded live ranges, no spill)
      const u16* P00 = apt + ((p*GG+D.i0)*GG+H.i0)*CAPP;
      const u16* P01 = apt + ((p*GG+D.i0)*GG+H.i1)*CAPP;
      const u16* P10 = apt + ((p*GG+D.i1)*GG+H.i0)*CAPP;
      const u16* P11 = apt + ((p*GG+D.i1)*GG+H.i1)*CAPP;
      const u16* L0  = alt + (p*GG+D.i0)*CAPP;
      const u16* L1  = alt + (p*GG+D.i1)*CAPP;
      #pragma unroll 2
      for (int g = 0; g < 6; g++){
        float ft[8];
        sample8(P00+g*8, P01+g*8, P10+g*8, P11+g*8, L0+g*8, L1+g*8,
                w00,w01,w10,w11, fd, ft);
        uint4 d;
        d.x = (u32)f2bf(ft[0]) | ((u32)f2bf(ft[1]) << 16);
        d.y = (u32)f2bf(ft[2]) | ((u32)f2bf(ft[3]) << 16);
        d.z = (u32)f2bf(ft[4]) | ((u32)f2bf(ft[5]) << 16);
        d.w = (u32)f2bf(ft[6]) | ((u32)f2bf(ft[7]) << 16);
        *(uint4*)(Arow + g*8) = d;
      }
    }

    // compiler-only fence: LDS ops within a wave complete in order in HW.
    asm volatile("" ::: "memory");

    #pragma unroll
    for (int t = 0; t < 4; t++){
      const u16* ab = Awave + (t*16 + (lane & 15))*TK + ((lane >> 4) * 8);
      s16x8 a0 = __builtin_bit_cast(s16x8, *(const uint4*)ab);
      s16x8 a1 = __builtin_bit_cast(s16x8, *(const uint4*)(ab + 32));
      acc[t][0] = __builtin_amdgcn_mfma_f32_16x16x32_bf16(a0, __builtin_bit_cast(s16x8,b00), acc[t][0], 0,0,0);
      acc[t][0] = __builtin_amdgcn_mfma_f32_16x16x32_bf16(a1, __builtin_bit_cast(s16x8,b01), acc[t][0], 0,0,0);
      acc[t][1] = __builtin_amdgcn_mfma_f32_16x16x32_bf16(a0, __builtin_bit_cast(s16x8,b10), acc[t][1], 0,0,0);
      acc[t][1] = __builtin_amdgcn_mfma_f32_16x16x32_bf16(a1, __builtin_bit_cast(s16x8,b11), acc[t][1], 0,0,0);
    }
    asm volatile("" ::: "memory");   // keep next plane's LDS writes below these reads
  }

  outv[pn] = sigma;

  float* ao = outv + NPTS;
  #pragma unroll
  for (int t = 0; t < 4; t++){
    #pragma unroll
    for (int nt = 0; nt < 2; nt++){
      int a = nt*16 + (lane & 15);
      #pragma unroll
      for (int r = 0; r < 4; r++){
        int src = t*16 + (lane >> 4)*4 + r;
        int pr = __shfl(pn, src);
        if (a < ADIM)
          ao[(size_t)pr*ADIM + a] = acc[t][nt][r];
      }
    }
  }
}

// ---- fallback: direct fp32 sampling ----
__global__ void sample_naive(const float* __restrict__ xyz,
    const float* __restrict__ dp, const float* __restrict__ dl,
    const float* __restrict__ ap, const float* __restrict__ al,
    const float* __restrict__ W,  float* __restrict__ outv)
{
  int n = blockIdx.x*blockDim.x + threadIdx.x;
  if (n >= NPTS) return;
  float X = xyz[3*n], Y = xyz[3*n+1], Z = xyz[3*n+2];
  float dco[3] = {Z, Y, X};
  float hco[3] = {Y, Z, Z};
  float sigma = 0.f, acc[ADIM];
  for (int a = 0; a < ADIM; a++) acc[a] = 0.f;
  for (int p = 0; p < 3; p++){
    IdxW D = idxw(dco[p]), H = idxw(hco[p]);
    float fd = D.f, fh = H.f;
    float w00=(1.f-fd)*(1.f-fh), w01=(1.f-fd)*fh, w10=fd*(1.f-fh), w11=fd*fh;
    for (int c = 0; c < CDEN; c++){
      const float* pl = dp + (size_t)(p*CDEN + c)*GG*GG;
      float pv = w00*pl[D.i0*GG+H.i0] + w01*pl[D.i0*GG+H.i1]
               + w10*pl[D.i1*GG+H.i0] + w11*pl[D.i1*GG+H.i1];
      const float* ll = dl + (p*CDEN + c)*GG;
      sigma += pv * (ll[D.i0] + fd*(ll[D.i1] - ll[D.i0]));
    }
    for (int c = 0; c < CAPP; c++){
      const float* pl = ap + (size_t)(p*CAPP + c)*GG*GG;
      float pv = w00*pl[D.i0*GG+H.i0] + w01*pl[D.i0*GG+H.i1]
               + w10*pl[D.i1*GG+H.i0] + w11*pl[D.i1*GG+H.i1];
      const float* ll = al + (p*CAPP + c)*GG;
      float ft = pv * (ll[D.i0] + fd*(ll[D.i1] - ll[D.i0]));
      int k = p*CAPP + c;
      for (int a = 0; a < ADIM; a++) acc[a] = fmaf(ft, W[a*KTOT + k], acc[a]);
    }
  }
  outv[n] = sigma;
  for (int a = 0; a < ADIM; a++) outv[NPTS + (size_t)n*ADIM + a] = acc[a];
}

extern "C" void kernel_launch(void* const* d_in, const int* in_sizes, int n_in,
                              void* d_out, int out_size, void* d_ws, size_t ws_size,
                              hipStream_t stream){
  const float* xyz    = (const float*)d_in[0];
  const float* dplane = (const float*)d_in[1];
  const float* dline  = (const float*)d_in[2];
  const float* aplane = (const float*)d_in[3];
  const float* aline  = (const float*)d_in[4];
  const float* W      = (const float*)d_in[5];
  float* outv = (float*)d_out;

  const size_t sz_dpt  = (size_t)3*GG*GG*CDEN*2;
  const size_t sz_apt  = (size_t)3*GG*GG*CAPP*2;
  const size_t sz_dlt  = (size_t)3*GG*CDEN*2;
  const size_t sz_alt  = (size_t)3*GG*CAPP*2;
  const size_t sz_bfr  = (size_t)3*2*2*64*16;
  const size_t sz_hist = (size_t)NBUCK_PAD*4;
  const size_t sz_offs = (size_t)NBUCK_PAD*4;
  const size_t sz_csum = (size_t)NCHUNK*4;
  const size_t sz_keys = (size_t)NPTS*4;
  const size_t sz_xyzq = (size_t)NPTS*16;

  const size_t off_apt  = sz_dpt;
  const size_t off_dlt  = off_apt + sz_apt;
  const size_t off_alt  = off_dlt + sz_dlt;
  const size_t off_bfr  = off_alt + sz_alt;
  const size_t off_hist = off_bfr + sz_bfr;
  const size_t off_offs = off_hist + sz_hist;
  const size_t off_csum = off_offs + sz_offs;
  const size_t off_keys = off_csum + sz_csum;
  const size_t off_xyzq = off_keys + sz_keys;
  const size_t need_tab  = off_hist;
  const size_t need_full = off_xyzq + sz_xyzq;

  if (ws_size < need_tab){
    sample_naive<<<(NPTS+255)/256, 256, 0, stream>>>(xyz, dplane, dline, aplane, aline, W, outv);
    return;
  }

  u16*   dpt = (u16*)((char*)d_ws);
  u16*   apt = (u16*)((char*)d_ws + off_apt);
  u16*   dlt = (u16*)((char*)d_ws + off_dlt);
  u16*   alt = (u16*)((char*)d_ws + off_alt);
  uint4* bfr = (uint4*)((char*)d_ws + off_bfr);

  if (ws_size < need_full){
    prep_all<<<2*TPBLK + 7, 256, 0, stream>>>(dplane, aplane, dline, aline, W, xyz,
                                              dpt, apt, dlt, alt, bfr, nullptr, nullptr);
    sample_mfma<false><<<NBLK64, 64, 0, stream>>>(nullptr, xyz, dpt, apt, dlt, alt, bfr, outv);
    return;
  }

  u32*    hist = (u32*)((char*)d_ws + off_hist);
  u32*    offs = (u32*)((char*)d_ws + off_offs);
  u32*    csum = (u32*)((char*)d_ws + off_csum);
  u32*    keys = (u32*)((char*)d_ws + off_keys);
  float4* xyzq = (float4*)((char*)d_ws + off_xyzq);

  hipMemsetAsync(hist, 0, sz_hist, stream);
  prep_all<<<2*TPBLK + 7 + NBLK, 256, 0, stream>>>(dplane, aplane, dline, aline, W, xyz,
                                                   dpt, apt, dlt, alt, bfr, hist, keys);
  scan1<<<NCHUNK, 1024, 0, stream>>>(hist, offs, csum);
  scatter_pts<<<NBLK, 256, 0, stream>>>(xyz, keys, offs, csum, xyzq);
  sample_mfma<true><<<NBLK64, 64, 0, stream>>>(xyzq, nullptr, dpt, apt, dlt, alt, bfr, outv);
}

// Round 14
// 176.010 us; speedup vs baseline: 1.1922x; 1.1477x over previous
//
#include <hip/hip_runtime.h>

#define GG    300
#define NPTS  524288
#define CDEN  16
#define CAPP  48
#define ADIM  27
#define KTOT  144
#define TK    72      // LDS A row stride in bf16: cols 0..47 data, 48..63 zero, 64..71 pad
#define NBUCK     90000          // linear key = ycell*300 + zcell
#define NBUCK_PAD 90112          // 88 * 1024
#define NCHUNK    88
#define NBLK  (NPTS/256)
#define NBLK64 (NPTS/64)
#define CHUNK64 (NBLK64/8)
#define TPBLK ((3*GG*GG + 255)/256)   // 1055

typedef unsigned int u32;
typedef unsigned short u16;
typedef unsigned char u8;
typedef __attribute__((ext_vector_type(8))) short s16x8;
typedef __attribute__((ext_vector_type(4))) float f32x4;
typedef __attribute__((ext_vector_type(2))) float f32x2;

__device__ __forceinline__ u16 f2bf(float f){
  u32 u = __float_as_uint(f);
  u32 r = u + 0x7FFFu + ((u >> 16) & 1u);   // RNE
  return (u16)(r >> 16);
}
__device__ __forceinline__ float bflo(u32 u){ return __uint_as_float(u << 16); }
__device__ __forceinline__ float bfhi(u32 u){ return __uint_as_float(u & 0xFFFF0000u); }

struct IdxW { int i0, i1; float f; };
__device__ __forceinline__ IdxW idxw(float c){
  float x  = (c + 1.0f) * 0.5f * (float)(GG - 1);
  float x0 = floorf(x);
  IdxW r;
  r.f = x - x0;
  int i0 = (int)x0;
  i0 = i0 < 0 ? 0 : (i0 > GG-1 ? GG-1 : i0);
  int i1 = i0 + 1; if (i1 > GG-1) i1 = GG-1;
  r.i0 = i0; r.i1 = i1;
  return r;
}
__device__ __forceinline__ int cell_of(float c){
  float x = (c + 1.0f) * 0.5f * (float)(GG - 1);
  int i = (int)floorf(x);
  return i < 0 ? 0 : (i > GG-1 ? GG-1 : i);
}

// sample 8 channels (bf16 plane+line) -> ft[0..7]  (density path)
__device__ __forceinline__ void sample8(const u16* P00, const u16* P01,
    const u16* P10, const u16* P11, const u16* L0, const u16* L1,
    float w00, float w01, float w10, float w11, float fd, float* ft)
{
  uint4 u00 = *(const uint4*)P00;
  uint4 u01 = *(const uint4*)P01;
  uint4 u10 = *(const uint4*)P10;
  uint4 u11 = *(const uint4*)P11;
  uint4 ul0 = *(const uint4*)L0;
  uint4 ul1 = *(const uint4*)L1;
  u32 a00[4]={u00.x,u00.y,u00.z,u00.w};
  u32 a01[4]={u01.x,u01.y,u01.z,u01.w};
  u32 a10[4]={u10.x,u10.y,u10.z,u10.w};
  u32 a11[4]={u11.x,u11.y,u11.z,u11.w};
  u32 al0[4]={ul0.x,ul0.y,ul0.z,ul0.w};
  u32 al1[4]={ul1.x,ul1.y,ul1.z,ul1.w};
  #pragma unroll
  for (int i = 0; i < 4; i++){
    float plo = w00*bflo(a00[i]) + w01*bflo(a01[i]) + w10*bflo(a10[i]) + w11*bflo(a11[i]);
    float phi = w00*bfhi(a00[i]) + w01*bfhi(a01[i]) + w10*bfhi(a10[i]) + w11*bfhi(a11[i]);
    float l0l = bflo(al0[i]), l1l = bflo(al1[i]);
    float l0h = bfhi(al0[i]), l1h = bfhi(al1[i]);
    ft[2*i+0] = plo * (l0l + fd*(l1l - l0l));
    ft[2*i+1] = phi * (l0h + fd*(l1h - l0h));
  }
}

// ---- fused prep: LDS-staged transposes (den bf16, app FP8) + lines + B-frags + hist ----
__global__ __launch_bounds__(256) void prep_all(
    const float* __restrict__ dplane, const float* __restrict__ aplane,
    const float* __restrict__ dline,  const float* __restrict__ aline,
    const float* __restrict__ W,      const float* __restrict__ xyz,
    u16* __restrict__ dpt, u8* __restrict__ apt,
    u16* __restrict__ dlt, u16* __restrict__ alt,
    uint4* __restrict__ Bfr, u32* __restrict__ hist, u32* __restrict__ keys)
{
  __shared__ __align__(16) u8 T8[256*64];   // 16 KB staging, 64B row stride
  const int b = blockIdx.x;
  const int tid = threadIdx.x;
  if (b < TPBLK){
    // density plane transpose [3][16][G*G] f32 -> [cell][16] bf16
    const int cell0 = b*256;
    const int ncell = min(256, 3*GG*GG - cell0);
    const int cell  = cell0 + tid;
    if (tid < ncell){
      int p = cell/(GG*GG), rem = cell - p*(GG*GG);
      u16 tmp[CDEN];
      #pragma unroll
      for (int c = 0; c < CDEN; c++)
        tmp[c] = f2bf(dplane[((size_t)(p*CDEN+c))*(GG*GG) + rem]);
      uint4 q0, q1;
      q0.x=(u32)tmp[0]|((u32)tmp[1]<<16);  q0.y=(u32)tmp[2]|((u32)tmp[3]<<16);
      q0.z=(u32)tmp[4]|((u32)tmp[5]<<16);  q0.w=(u32)tmp[6]|((u32)tmp[7]<<16);
      q1.x=(u32)tmp[8]|((u32)tmp[9]<<16);  q1.y=(u32)tmp[10]|((u32)tmp[11]<<16);
      q1.z=(u32)tmp[12]|((u32)tmp[13]<<16); q1.w=(u32)tmp[14]|((u32)tmp[15]<<16);
      u8* Trow = T8 + tid*64;
      *(uint4*)(Trow +  0) = q0;
      *(uint4*)(Trow + 16) = q1;
    }
    __syncthreads();
    uint2* dst = (uint2*)(dpt + (size_t)cell0*CDEN);
    const int nch = ncell*4;                 // 8B chunks (32B/cell)
    #pragma unroll
    for (int k = 0; k < 4; k++){
      int idx = k*256 + tid;
      if (idx < nch){
        int cl = idx >> 2, j = idx & 3;
        dst[idx] = *(const uint2*)(T8 + cl*64 + j*8);
      }
    }
  } else if (b < 2*TPBLK){
    // app plane transpose [3][48][G*G] f32 -> [cell][48] FP8 e4m3 (HW cvt)
    const int cell0 = (b - TPBLK)*256;
    const int ncell = min(256, 3*GG*GG - cell0);
    const int cell  = cell0 + tid;
    if (tid < ncell){
      int p = cell/(GG*GG), rem = cell - p*(GG*GG);
      u32 wbuf[12];
      #pragma unroll
      for (int c2 = 0; c2 < 12; c2++){
        float f0 = aplane[((size_t)(p*CAPP + c2*4+0))*(GG*GG) + rem];
        float f1 = aplane[((size_t)(p*CAPP + c2*4+1))*(GG*GG) + rem];
        float f2 = aplane[((size_t)(p*CAPP + c2*4+2))*(GG*GG) + rem];
        float f3 = aplane[((size_t)(p*CAPP + c2*4+3))*(GG*GG) + rem];
        int w = 0;
        w = __builtin_amdgcn_cvt_pk_fp8_f32(f0, f1, w, false);
        w = __builtin_amdgcn_cvt_pk_fp8_f32(f2, f3, w, true);
        wbuf[c2] = (u32)w;
      }
      u8* Trow = T8 + tid*64;
      *(uint4*)(Trow +  0) = make_uint4(wbuf[0],wbuf[1],wbuf[2],wbuf[3]);
      *(uint4*)(Trow + 16) = make_uint4(wbuf[4],wbuf[5],wbuf[6],wbuf[7]);
      *(uint4*)(Trow + 32) = make_uint4(wbuf[8],wbuf[9],wbuf[10],wbuf[11]);
    }
    __syncthreads();
    uint2* dst = (uint2*)(apt + (size_t)cell0*48);
    const int nch = ncell*6;                 // 8B chunks (48B/cell)
    #pragma unroll
    for (int k = 0; k < 6; k++){
      int idx = k*256 + tid;
      if (idx < nch){
        int cl = idx/6, j = idx - cl*6;
        dst[idx] = *(const uint2*)(T8 + cl*64 + j*8);
      }
    }
  } else if (b < 2*TPBLK + 4){
    int t = (b - 2*TPBLK)*256 + tid;
    if (t < 3*GG){
      int p = t / GG, d = t - p*GG;
      #pragma unroll
      for (int c = 0; c < CDEN; c++) dlt[t*CDEN + c] = f2bf(dline[(p*CDEN + c)*GG + d]);
      #pragma unroll
      for (int c = 0; c < CAPP; c++) alt[t*CAPP + c] = f2bf(aline[(p*CAPP + c)*GG + d]);
    }
  } else if (b < 2*TPBLK + 7){
    int t = (b - (2*TPBLK + 4))*256 + tid;
    if (t < 3*2*2*64){
      int lane = t & 63;
      int st = (t >> 6) & 1;
      int nt = (t >> 7) & 1;
      int p  = t >> 8;
      int a  = nt*16 + (lane & 15);
      int kb = st*32 + ((lane >> 4) * 8);
      u32 d[4];
      #pragma unroll
      for (int j2 = 0; j2 < 4; j2++){
        int k0 = kb + 2*j2, k1 = k0 + 1;
        u32 lo = (a < ADIM && k0 < 48) ? (u32)f2bf(W[a*KTOT + p*48 + k0]) : 0u;
        u32 hi = (a < ADIM && k1 < 48) ? (u32)f2bf(W[a*KTOT + p*48 + k1]) : 0u;
        d[j2] = lo | (hi << 16);
      }
      Bfr[t] = make_uint4(d[0], d[1], d[2], d[3]);
    }
  } else {
    int n = (b - (2*TPBLK + 7))*256 + tid;
    float Y = xyz[3*n+1], Z = xyz[3*n+2];
    u32 key = (u32)cell_of(Y)*300u + (u32)cell_of(Z);
    keys[n] = key;
    atomicAdd(&hist[key], 1u);
  }
}

// ---- scan1: per-1024-chunk exclusive scan (88 blocks, coalesced) ----
__global__ __launch_bounds__(1024) void scan1(const u32* __restrict__ hist,
                                              u32* __restrict__ offs,
                                              u32* __restrict__ csum){
  __shared__ u32 part[1024];
  const int t = threadIdx.x;
  const int i = blockIdx.x*1024 + t;
  u32 v = hist[i];
  part[t] = v;
  __syncthreads();
  for (int off = 1; off < 1024; off <<= 1){
    u32 x = (t >= off) ? part[t - off] : 0;
    __syncthreads();
    part[t] += x;
    __syncthreads();
  }
  offs[i] = part[t] - v;
  if (t == 1023) csum[blockIdx.x] = part[t];
}

// ---- scatter with inline chunk-base scan ----
__global__ __launch_bounds__(256) void scatter_pts(const float* __restrict__ xyz,
                                                   const u32* __restrict__ keys,
                                                   u32* __restrict__ offs,
                                                   const u32* __restrict__ csum,
                                                   float4* __restrict__ xyzq){
  __shared__ u32 part[128];
  __shared__ u32 cb[NCHUNK];
  const int t = threadIdx.x;
  u32 cv = 0;
  if (t < 128){
    cv = (t < NCHUNK) ? csum[t] : 0;
    part[t] = cv;
  }
  __syncthreads();
  for (int off = 1; off < 128; off <<= 1){
    u32 x = 0;
    if (t < 128 && t >= off) x = part[t - off];
    __syncthreads();
    if (t < 128) part[t] += x;
    __syncthreads();
  }
  if (t < NCHUNK) cb[t] = part[t] - cv;
  __syncthreads();

  int n = blockIdx.x*256 + t;
  u32 key = keys[n];
  u32 pos = cb[key >> 10] + atomicAdd(&offs[key], 1u);
  float4 q;
  q.x = xyz[3*n+0]; q.y = xyz[3*n+1]; q.z = xyz[3*n+2];
  q.w = __int_as_float(n);
  xyzq[pos] = q;
}

// ---- main: fused sampling + per-wave MFMA GEMM. ONE WAVE PER BLOCK ----
// R14: app PLANES in fp8 e4m3 -> 48B/row = 1 load per 16-ch group (was 2).
// Instr count/pt: 144 -> 108 (den bf16 12 + app 24 per plane). TA model 92us.
// Den + lines stay bf16 (sigma accuracy). DO NOT add the 2nd launch_bounds
// arg (R4: spill; R8: miscompute). Kernel is L1/TA lane-slot bound:
// insensitive to occupancy/ILP/sharing/LDS-redistribution (R5-R12).
template<bool SORTED>
__global__ __launch_bounds__(64) void sample_mfma(
    const float4* __restrict__ xyzq,
    const float* __restrict__ xyz,
    const u16*  __restrict__ dpt,
    const u8*   __restrict__ apt,   // [3][G][G][48] fp8
    const u16*  __restrict__ dlt,
    const u16*  __restrict__ alt,
    const uint4* __restrict__ Bfr,
    float* __restrict__ outv)
{
  __shared__ __align__(16) u16 Asm[64*TK];   // 9216 B, wave-private
  const int lane = threadIdx.x;
  int bid = blockIdx.x;
  if (SORTED) bid = (bid & 7)*CHUNK64 + (bid >> 3);
  const int n = bid*64 + lane;

  float X, Y, Z; int pn;
  if (SORTED){
    float4 q = xyzq[n];
    X = q.x; Y = q.y; Z = q.z; pn = __float_as_int(q.w);
  } else {
    X = xyz[3*n+0]; Y = xyz[3*n+1]; Z = xyz[3*n+2]; pn = n;
  }

  u16* Arow = Asm + lane*TK;
  const u16* Awave = Asm;

  float sigma = 0.f;
  f32x4 acc[4][2];
  #pragma unroll
  for (int t = 0; t < 4; t++){
    acc[t][0] = (f32x4){0.f,0.f,0.f,0.f};
    acc[t][1] = (f32x4){0.f,0.f,0.f,0.f};
  }

  uint4 z4 = make_uint4(0,0,0,0);
  *(uint4*)(Arow + 48) = z4;
  *(uint4*)(Arow + 56) = z4;

  #pragma unroll 1
  for (int p = 0; p < 3; p++){
    const float dc = (p==0) ? Z : ((p==1) ? Y : X);
    const float hc = (p==0) ? Y : Z;

    uint4 b00 = Bfr[(p*4 + 0)*64 + lane];
    uint4 b01 = Bfr[(p*4 + 1)*64 + lane];
    uint4 b10 = Bfr[(p*4 + 2)*64 + lane];
    uint4 b11 = Bfr[(p*4 + 3)*64 + lane];

    IdxW D = idxw(dc), H = idxw(hc);
    const float fd = D.f, fh = H.f;
    const float w00 = (1.f-fd)*(1.f-fh), w01 = (1.f-fd)*fh;
    const float w10 = fd*(1.f-fh),       w11 = fd*fh;

    { // density -> sigma (bf16)
      const u16* P00 = dpt + ((p*GG+D.i0)*GG+H.i0)*CDEN;
      const u16* P01 = dpt + ((p*GG+D.i0)*GG+H.i1)*CDEN;
      const u16* P10 = dpt + ((p*GG+D.i1)*GG+H.i0)*CDEN;
      const u16* P11 = dpt + ((p*GG+D.i1)*GG+H.i1)*CDEN;
      const u16* L0  = dlt + (p*GG+D.i0)*CDEN;
      const u16* L1  = dlt + (p*GG+D.i1)*CDEN;
      #pragma unroll
      for (int g = 0; g < 2; g++){
        float ft[8];
        sample8(P00+g*8, P01+g*8, P10+g*8, P11+g*8, L0+g*8, L1+g*8,
                w00,w01,w10,w11, fd, ft);
        sigma += ((ft[0]+ft[1])+(ft[2]+ft[3])) + ((ft[4]+ft[5])+(ft[6]+ft[7]));
      }
    }

    { // app feats: fp8 plane corners + bf16 lines -> LDS A tile
      const u8* C00 = apt + ((size_t)((p*GG+D.i0)*GG+H.i0))*48;
      const u8* C01 = apt + ((size_t)((p*GG+D.i0)*GG+H.i1))*48;
      const u8* C10 = apt + ((size_t)((p*GG+D.i1)*GG+H.i0))*48;
      const u8* C11 = apt + ((size_t)((p*GG+D.i1)*GG+H.i1))*48;
      const u16* L0  = alt + (p*GG+D.i0)*CAPP;
      const u16* L1  = alt + (p*GG+D.i1)*CAPP;
      #pragma unroll 1
      for (int g = 0; g < 3; g++){
        uint4 q00 = *(const uint4*)(C00 + g*16);   // 16 fp8 channels
        uint4 q01 = *(const uint4*)(C01 + g*16);
        uint4 q10 = *(const uint4*)(C10 + g*16);
        uint4 q11 = *(const uint4*)(C11 + g*16);
        uint4 la  = *(const uint4*)(L0 + g*16);    // ch 0..7 (bf16)
        uint4 lb  = *(const uint4*)(L0 + g*16 + 8);// ch 8..15
        uint4 lc  = *(const uint4*)(L1 + g*16);
        uint4 ld  = *(const uint4*)(L1 + g*16 + 8);
        u32 a00[4]={q00.x,q00.y,q00.z,q00.w};
        u32 a01[4]={q01.x,q01.y,q01.z,q01.w};
        u32 a10[4]={q10.x,q10.y,q10.z,q10.w};
        u32 a11[4]={q11.x,q11.y,q11.z,q11.w};
        u32 l0w[8]={la.x,la.y,la.z,la.w,lb.x,lb.y,lb.z,lb.w};
        u32 l1w[8]={lc.x,lc.y,lc.z,lc.w,ld.x,ld.y,ld.z,ld.w};
        float ft[16];
        #pragma unroll
        for (int w = 0; w < 4; w++){
          f32x2 p00a = __builtin_amdgcn_cvt_pk_f32_fp8((int)a00[w], false);
          f32x2 p00b = __builtin_amdgcn_cvt_pk_f32_fp8((int)a00[w], true);
          f32x2 p01a = __builtin_amdgcn_cvt_pk_f32_fp8((int)a01[w], false);
          f32x2 p01b = __builtin_amdgcn_cvt_pk_f32_fp8((int)a01[w], true);
          f32x2 p10a = __builtin_amdgcn_cvt_pk_f32_fp8((int)a10[w], false);
          f32x2 p10b = __builtin_amdgcn_cvt_pk_f32_fp8((int)a10[w], true);
          f32x2 p11a = __builtin_amdgcn_cvt_pk_f32_fp8((int)a11[w], false);
          f32x2 p11b = __builtin_amdgcn_cvt_pk_f32_fp8((int)a11[w], true);
          u32 lu0 = l0w[2*w], lu1 = l0w[2*w+1];
          u32 lv0 = l1w[2*w], lv1 = l1w[2*w+1];
          float pv0 = w00*p00a.x + w01*p01a.x + w10*p10a.x + w11*p11a.x;
          float pv1 = w00*p00a.y + w01*p01a.y + w10*p10a.y + w11*p11a.y;
          float pv2 = w00*p00b.x + w01*p01b.x + w10*p10b.x + w11*p11b.x;
          float pv3 = w00*p00b.y + w01*p01b.y + w10*p10b.y + w11*p11b.y;
          float l00=bflo(lu0), l01=bfhi(lu0), l02=bflo(lu1), l03=bfhi(lu1);
          float m00=bflo(lv0), m01=bfhi(lv0), m02=bflo(lv1), m03=bfhi(lv1);
          ft[4*w+0] = pv0 * (l00 + fd*(m00 - l00));
          ft[4*w+1] = pv1 * (l01 + fd*(m01 - l01));
          ft[4*w+2] = pv2 * (l02 + fd*(m02 - l02));
          ft[4*w+3] = pv3 * (l03 + fd*(m03 - l03));
        }
        uint4 d0, d1;
        d0.x=(u32)f2bf(ft[0])|((u32)f2bf(ft[1])<<16);
        d0.y=(u32)f2bf(ft[2])|((u32)f2bf(ft[3])<<16);
        d0.z=(u32)f2bf(ft[4])|((u32)f2bf(ft[5])<<16);
        d0.w=(u32)f2bf(ft[6])|((u32)f2bf(ft[7])<<16);
        d1.x=(u32)f2bf(ft[8])|((u32)f2bf(ft[9])<<16);
        d1.y=(u32)f2bf(ft[10])|((u32)f2bf(ft[11])<<16);
        d1.z=(u32)f2bf(ft[12])|((u32)f2bf(ft[13])<<16);
        d1.w=(u32)f2bf(ft[14])|((u32)f2bf(ft[15])<<16);
        *(uint4*)(Arow + g*16)     = d0;
        *(uint4*)(Arow + g*16 + 8) = d1;
      }
    }

    // compiler-only fence: LDS ops within a wave complete in order in HW.
    asm volatile("" ::: "memory");

    #pragma unroll
    for (int t = 0; t < 4; t++){
      const u16* ab = Awave + (t*16 + (lane & 15))*TK + ((lane >> 4) * 8);
      s16x8 a0 = __builtin_bit_cast(s16x8, *(const uint4*)ab);
      s16x8 a1 = __builtin_bit_cast(s16x8, *(const uint4*)(ab + 32));
      acc[t][0] = __builtin_amdgcn_mfma_f32_16x16x32_bf16(a0, __builtin_bit_cast(s16x8,b00), acc[t][0], 0,0,0);
      acc[t][0] = __builtin_amdgcn_mfma_f32_16x16x32_bf16(a1, __builtin_bit_cast(s16x8,b01), acc[t][0], 0,0,0);
      acc[t][1] = __builtin_amdgcn_mfma_f32_16x16x32_bf16(a0, __builtin_bit_cast(s16x8,b10), acc[t][1], 0,0,0);
      acc[t][1] = __builtin_amdgcn_mfma_f32_16x16x32_bf16(a1, __builtin_bit_cast(s16x8,b11), acc[t][1], 0,0,0);
    }
    asm volatile("" ::: "memory");   // keep next plane's LDS writes below these reads
  }

  outv[pn] = sigma;

  float* ao = outv + NPTS;
  #pragma unroll
  for (int t = 0; t < 4; t++){
    #pragma unroll
    for (int nt = 0; nt < 2; nt++){
      int a = nt*16 + (lane & 15);
      #pragma unroll
      for (int r = 0; r < 4; r++){
        int src = t*16 + (lane >> 4)*4 + r;
        int pr = __shfl(pn, src);
        if (a < ADIM)
          ao[(size_t)pr*ADIM + a] = acc[t][nt][r];
      }
    }
  }
}

// ---- fallback: direct fp32 sampling ----
__global__ void sample_naive(const float* __restrict__ xyz,
    const float* __restrict__ dp, const float* __restrict__ dl,
    const float* __restrict__ ap, const float* __restrict__ al,
    const float* __restrict__ W,  float* __restrict__ outv)
{
  int n = blockIdx.x*blockDim.x + threadIdx.x;
  if (n >= NPTS) return;
  float X = xyz[3*n], Y = xyz[3*n+1], Z = xyz[3*n+2];
  float dco[3] = {Z, Y, X};
  float hco[3] = {Y, Z, Z};
  float sigma = 0.f, acc[ADIM];
  for (int a = 0; a < ADIM; a++) acc[a] = 0.f;
  for (int p = 0; p < 3; p++){
    IdxW D = idxw(dco[p]), H = idxw(hco[p]);
    float fd = D.f, fh = H.f;
    float w00=(1.f-fd)*(1.f-fh), w01=(1.f-fd)*fh, w10=fd*(1.f-fh), w11=fd*fh;
    for (int c = 0; c < CDEN; c++){
      const float* pl = dp + (size_t)(p*CDEN + c)*GG*GG;
      float pv = w00*pl[D.i0*GG+H.i0] + w01*pl[D.i0*GG+H.i1]
               + w10*pl[D.i1*GG+H.i0] + w11*pl[D.i1*GG+H.i1];
      const float* ll = dl + (p*CDEN + c)*GG;
      sigma += pv * (ll[D.i0] + fd*(ll[D.i1] - ll[D.i0]));
    }
    for (int c = 0; c < CAPP; c++){
      const float* pl = ap + (size_t)(p*CAPP + c)*GG*GG;
      float pv = w00*pl[D.i0*GG+H.i0] + w01*pl[D.i0*GG+H.i1]
               + w10*pl[D.i1*GG+H.i0] + w11*pl[D.i1*GG+H.i1];
      const float* ll = al + (p*CAPP + c)*GG;
      float ft = pv * (ll[D.i0] + fd*(ll[D.i1] - ll[D.i0]));
      int k = p*CAPP + c;
      for (int a = 0; a < ADIM; a++) acc[a] = fmaf(ft, W[a*KTOT + k], acc[a]);
    }
  }
  outv[n] = sigma;
  for (int a = 0; a < ADIM; a++) outv[NPTS + (size_t)n*ADIM + a] = acc[a];
}

extern "C" void kernel_launch(void* const* d_in, const int* in_sizes, int n_in,
                              void* d_out, int out_size, void* d_ws, size_t ws_size,
                              hipStream_t stream){
  const float* xyz    = (const float*)d_in[0];
  const float* dplane = (const float*)d_in[1];
  const float* dline  = (const float*)d_in[2];
  const float* aplane = (const float*)d_in[3];
  const float* aline  = (const float*)d_in[4];
  const float* W      = (const float*)d_in[5];
  float* outv = (float*)d_out;

  const size_t sz_dpt  = (size_t)3*GG*GG*CDEN*2;
  const size_t sz_apt  = (size_t)3*GG*GG*48;      // fp8: 12,960,000
  const size_t sz_dlt  = (size_t)3*GG*CDEN*2;
  const size_t sz_alt  = (size_t)3*GG*CAPP*2;
  const size_t sz_bfr  = (size_t)3*2*2*64*16;
  const size_t sz_hist = (size_t)NBUCK_PAD*4;
  const size_t sz_offs = (size_t)NBUCK_PAD*4;
  const size_t sz_csum = (size_t)NCHUNK*4;
  const size_t sz_keys = (size_t)NPTS*4;
  const size_t sz_xyzq = (size_t)NPTS*16;

  const size_t off_apt  = sz_dpt;
  const size_t off_dlt  = off_apt + sz_apt;
  const size_t off_alt  = off_dlt + sz_dlt;
  const size_t off_bfr  = off_alt + sz_alt;
  const size_t off_hist = off_bfr + sz_bfr;
  const size_t off_offs = off_hist + sz_hist;
  const size_t off_csum = off_offs + sz_offs;
  const size_t off_keys = off_csum + sz_csum;
  const size_t off_xyzq = off_keys + sz_keys;
  const size_t need_tab  = off_hist;
  const size_t need_full = off_xyzq + sz_xyzq;

  if (ws_size < need_tab){
    sample_naive<<<(NPTS+255)/256, 256, 0, stream>>>(xyz, dplane, dline, aplane, aline, W, outv);
    return;
  }

  u16*   dpt = (u16*)((char*)d_ws);
  u8*    apt = (u8*)((char*)d_ws + off_apt);
  u16*   dlt = (u16*)((char*)d_ws + off_dlt);
  u16*   alt = (u16*)((char*)d_ws + off_alt);
  uint4* bfr = (uint4*)((char*)d_ws + off_bfr);

  if (ws_size < need_full){
    prep_all<<<2*TPBLK + 7, 256, 0, stream>>>(dplane, aplane, dline, aline, W, xyz,
                                              dpt, apt, dlt, alt, bfr, nullptr, nullptr);
    sample_mfma<false><<<NBLK64, 64, 0, stream>>>(nullptr, xyz, dpt, apt, dlt, alt, bfr, outv);
    return;
  }

  u32*    hist = (u32*)((char*)d_ws + off_hist);
  u32*    offs = (u32*)((char*)d_ws + off_offs);
  u32*    csum = (u32*)((char*)d_ws + off_csum);
  u32*    keys = (u32*)((char*)d_ws + off_keys);
  float4* xyzq = (float4*)((char*)d_ws + off_xyzq);

  hipMemsetAsync(hist, 0, sz_hist, stream);
  prep_all<<<2*TPBLK + 7 + NBLK, 256, 0, stream>>>(dplane, aplane, dline, aline, W, xyz,
                                                   dpt, apt, dlt, alt, bfr, hist, keys);
  scan1<<<NCHUNK, 1024, 0, stream>>>(hist, offs, csum);
  scatter_pts<<<NBLK, 256, 0, stream>>>(xyz, keys, offs, csum, xyzq);
  sample_mfma<true><<<NBLK64, 64, 0, stream>>>(xyzq, nullptr, dpt, apt, dlt, alt, bfr, outv);
}

// Round 16
// 154.487 us; speedup vs baseline: 1.3583x; 1.1393x over previous
//
#include <hip/hip_runtime.h>

#define GG    300
#define NPTS  524288
#define CDEN  16
#define CAPP  48
#define ADIM  27
#define KTOT  144
#define TK    72      // LDS A row stride in bf16: cols 0..47 data, 48..63 zero, 64..71 pad
#define NBUCK     90000          // linear key = ycell*300 + zcell
#define NBUCK_PAD 90112          // 88 * 1024
#define NCHUNK    88
#define NBLK  (NPTS/256)
#define NBLK64 (NPTS/64)
#define CHUNK64 (NBLK64/8)
#define TPBLK ((3*GG*GG + 255)/256)   // 1055

typedef unsigned int u32;
typedef unsigned short u16;
typedef unsigned char u8;
typedef __attribute__((ext_vector_type(8))) short s16x8;
typedef __attribute__((ext_vector_type(4))) float f32x4;
typedef __attribute__((ext_vector_type(2))) float f32x2;

__device__ __forceinline__ u16 f2bf(float f){
  u32 u = __float_as_uint(f);
  u32 r = u + 0x7FFFu + ((u >> 16) & 1u);   // RNE
  return (u16)(r >> 16);
}
__device__ __forceinline__ float bflo(u32 u){ return __uint_as_float(u << 16); }
__device__ __forceinline__ float bfhi(u32 u){ return __uint_as_float(u & 0xFFFF0000u); }

struct IdxW { int i0, i1; float f; };
__device__ __forceinline__ IdxW idxw(float c){
  float x  = (c + 1.0f) * 0.5f * (float)(GG - 1);
  float x0 = floorf(x);
  IdxW r;
  r.f = x - x0;
  int i0 = (int)x0;
  i0 = i0 < 0 ? 0 : (i0 > GG-1 ? GG-1 : i0);
  int i1 = i0 + 1; if (i1 > GG-1) i1 = GG-1;
  r.i0 = i0; r.i1 = i1;
  return r;
}
__device__ __forceinline__ int cell_of(float c){
  float x = (c + 1.0f) * 0.5f * (float)(GG - 1);
  int i = (int)floorf(x);
  return i < 0 ? 0 : (i > GG-1 ? GG-1 : i);
}

// ---- fused prep: density V-TABLE (fp32 dots -> bf16) + app fp8 + hist ----
// V0[d,h]=dot(dp[d,h],dl[d]); Vp=dot(.,dl[d+1]); Vm=dot(.,dl[d-1]).
// sigma needs only these (fd-linear combos) -> density drops from 6 loads +
// ~100 VALU to 4x8B loads + ~16 VALU per plane. fp32 dots: MORE accurate
// than per-channel bf16. Clamped-edge table entries always get weight fd=0.
__global__ __launch_bounds__(256) void prep_all(
    const float* __restrict__ dplane, const float* __restrict__ aplane,
    const float* __restrict__ dline,  const float* __restrict__ aline,
    const float* __restrict__ W,      const float* __restrict__ xyz,
    uint2* __restrict__ Vt, u8* __restrict__ apt, u8* __restrict__ alt,
    uint4* __restrict__ Bfr, u32* __restrict__ hist, u32* __restrict__ keys)
{
  __shared__ __align__(16) u8 T8[256*64];   // 16 KB staging (app branch only)
  const int b = blockIdx.x;
  const int tid = threadIdx.x;
  if (b < TPBLK){
    // density V-table: cell -> (V0,Vp,Vm) bf16 packed in uint2
    const int cell = b*256 + tid;
    if (cell < 3*GG*GG){
      int p = cell/(GG*GG), rem = cell - p*(GG*GG);
      int d = rem/GG;
      int dp1 = d < GG-1 ? d+1 : GG-1;
      int dm  = d > 0    ? d-1 : 0;
      float v0 = 0.f, vp = 0.f, vm = 0.f;
      #pragma unroll
      for (int c = 0; c < CDEN; c++){
        float pv = dplane[((size_t)(p*CDEN+c))*(GG*GG) + rem];
        const float* ln = dline + (p*CDEN+c)*GG;
        v0 += pv * ln[d];
        vp += pv * ln[dp1];
        vm += pv * ln[dm];
      }
      uint2 q;
      q.x = (u32)f2bf(v0) | ((u32)f2bf(vp) << 16);
      q.y = (u32)f2bf(vm);
      Vt[cell] = q;
    }
  } else if (b < 2*TPBLK){
    // app plane transpose [3][48][G*G] f32 -> [cell][48] fp8
    const int cell0 = (b - TPBLK)*256;
    const int ncell = min(256, 3*GG*GG - cell0);
    const int cell  = cell0 + tid;
    if (tid < ncell){
      int p = cell/(GG*GG), rem = cell - p*(GG*GG);
      u32 wbuf[12];
      #pragma unroll
      for (int c2 = 0; c2 < 12; c2++){
        float f0 = aplane[((size_t)(p*CAPP + c2*4+0))*(GG*GG) + rem];
        float f1 = aplane[((size_t)(p*CAPP + c2*4+1))*(GG*GG) + rem];
        float f2 = aplane[((size_t)(p*CAPP + c2*4+2))*(GG*GG) + rem];
        float f3 = aplane[((size_t)(p*CAPP + c2*4+3))*(GG*GG) + rem];
        int w = 0;
        w = __builtin_amdgcn_cvt_pk_fp8_f32(f0, f1, w, false);
        w = __builtin_amdgcn_cvt_pk_fp8_f32(f2, f3, w, true);
        wbuf[c2] = (u32)w;
      }
      u8* Trow = T8 + tid*64;
      *(uint4*)(Trow +  0) = make_uint4(wbuf[0],wbuf[1],wbuf[2],wbuf[3]);
      *(uint4*)(Trow + 16) = make_uint4(wbuf[4],wbuf[5],wbuf[6],wbuf[7]);
      *(uint4*)(Trow + 32) = make_uint4(wbuf[8],wbuf[9],wbuf[10],wbuf[11]);
    }
    __syncthreads();
    uint2* dst = (uint2*)(apt + (size_t)cell0*48);
    const int nch = ncell*6;                 // 8B chunks (48B/cell)
    #pragma unroll
    for (int k = 0; k < 6; k++){
      int idx = k*256 + tid;
      if (idx < nch){
        int cl = idx/6, j = idx - cl*6;
        dst[idx] = *(const uint2*)(T8 + cl*64 + j*8);
      }
    }
  } else if (b < 2*TPBLK + 4){
    int t = (b - 2*TPBLK)*256 + tid;
    if (t < 3*GG){
      int p = t / GG, d = t - p*GG;
      u32 ab[12];
      #pragma unroll
      for (int c2 = 0; c2 < 12; c2++){
        float f0 = aline[(p*CAPP + c2*4+0)*GG + d];
        float f1 = aline[(p*CAPP + c2*4+1)*GG + d];
        float f2 = aline[(p*CAPP + c2*4+2)*GG + d];
        float f3 = aline[(p*CAPP + c2*4+3)*GG + d];
        int w = 0;
        w = __builtin_amdgcn_cvt_pk_fp8_f32(f0, f1, w, false);
        w = __builtin_amdgcn_cvt_pk_fp8_f32(f2, f3, w, true);
        ab[c2] = (u32)w;
      }
      *(uint4*)(alt + (size_t)t*48 +  0) = make_uint4(ab[0],ab[1],ab[2],ab[3]);
      *(uint4*)(alt + (size_t)t*48 + 16) = make_uint4(ab[4],ab[5],ab[6],ab[7]);
      *(uint4*)(alt + (size_t)t*48 + 32) = make_uint4(ab[8],ab[9],ab[10],ab[11]);
    }
  } else if (b < 2*TPBLK + 7){
    int t = (b - (2*TPBLK + 4))*256 + tid;
    if (t < 3*2*2*64){
      int lane = t & 63;
      int st = (t >> 6) & 1;
      int nt = (t >> 7) & 1;
      int p  = t >> 8;
      int a  = nt*16 + (lane & 15);
      int kb = st*32 + ((lane >> 4) * 8);
      u32 d[4];
      #pragma unroll
      for (int j2 = 0; j2 < 4; j2++){
        int k0 = kb + 2*j2, k1 = k0 + 1;
        u32 lo = (a < ADIM && k0 < 48) ? (u32)f2bf(W[a*KTOT + p*48 + k0]) : 0u;
        u32 hi = (a < ADIM && k1 < 48) ? (u32)f2bf(W[a*KTOT + p*48 + k1]) : 0u;
        d[j2] = lo | (hi << 16);
      }
      Bfr[t] = make_uint4(d[0], d[1], d[2], d[3]);
    }
  } else {
    int n = (b - (2*TPBLK + 7))*256 + tid;
    float Y = xyz[3*n+1], Z = xyz[3*n+2];
    u32 key = (u32)cell_of(Y)*300u + (u32)cell_of(Z);
    keys[n] = key;
    atomicAdd(&hist[key], 1u);
  }
}

// ---- scan1: per-1024-chunk exclusive scan (88 blocks, coalesced) ----
__global__ __launch_bounds__(1024) void scan1(const u32* __restrict__ hist,
                                              u32* __restrict__ offs,
                                              u32* __restrict__ csum){
  __shared__ u32 part[1024];
  const int t = threadIdx.x;
  const int i = blockIdx.x*1024 + t;
  u32 v = hist[i];
  part[t] = v;
  __syncthreads();
  for (int off = 1; off < 1024; off <<= 1){
    u32 x = (t >= off) ? part[t - off] : 0;
    __syncthreads();
    part[t] += x;
    __syncthreads();
  }
  offs[i] = part[t] - v;
  if (t == 1023) csum[blockIdx.x] = part[t];
}

// ---- scatter with inline chunk-base scan ----
__global__ __launch_bounds__(256) void scatter_pts(const float* __restrict__ xyz,
                                                   const u32* __restrict__ keys,
                                                   u32* __restrict__ offs,
                                                   const u32* __restrict__ csum,
                                                   float4* __restrict__ xyzq){
  __shared__ u32 part[128];
  __shared__ u32 cb[NCHUNK];
  const int t = threadIdx.x;
  u32 cv = 0;
  if (t < 128){
    cv = (t < NCHUNK) ? csum[t] : 0;
    part[t] = cv;
  }
  __syncthreads();
  for (int off = 1; off < 128; off <<= 1){
    u32 x = 0;
    if (t < 128 && t >= off) x = part[t - off];
    __syncthreads();
    if (t < 128) part[t] += x;
    __syncthreads();
  }
  if (t < NCHUNK) cb[t] = part[t] - cv;
  __syncthreads();

  int n = blockIdx.x*256 + t;
  u32 key = keys[n];
  u32 pos = cb[key >> 10] + atomicAdd(&offs[key], 1u);
  float4 q;
  q.x = xyz[3*n+0]; q.y = xyz[3*n+1]; q.z = xyz[3*n+2];
  q.w = __int_as_float(n);
  xyzq[pos] = q;
}

// ---- main: fused sampling + per-wave MFMA GEMM. ONE WAVE PER BLOCK ----
// R16: density via V-table (4x8B loads/plane), app fp8 corners + fp8 lines
// (18 loads/plane). 67 load-instrs/pt (was 108). Sigma keeps fp32-dot
// accuracy (R15's fp8xfp8 sigma failed at 1.22e-2: max-stats over 524288
// = ~5sigma of sqrt(48)*term-RMS; app tolerates fp8xfp8 via W's 1/12 scale).
// DO NOT add the 2nd launch_bounds arg (R4: spill; R8: miscompute).
template<bool SORTED>
__global__ __launch_bounds__(64) void sample_mfma(
    const float4* __restrict__ xyzq,
    const float* __restrict__ xyz,
    const uint2* __restrict__ Vt,   // [3][G][G] {V0,Vp | Vm,0} bf16
    const u8*   __restrict__ apt,   // [3][G][G][48] fp8
    const u8*   __restrict__ alt,   // [3][G][48] fp8
    const uint4* __restrict__ Bfr,
    float* __restrict__ outv)
{
  __shared__ __align__(16) u16 Asm[64*TK];   // 9216 B, wave-private
  const int lane = threadIdx.x;
  int bid = blockIdx.x;
  if (SORTED) bid = (bid & 7)*CHUNK64 + (bid >> 3);
  const int n = bid*64 + lane;

  float X, Y, Z; int pn;
  if (SORTED){
    float4 q = xyzq[n];
    X = q.x; Y = q.y; Z = q.z; pn = __float_as_int(q.w);
  } else {
    X = xyz[3*n+0]; Y = xyz[3*n+1]; Z = xyz[3*n+2]; pn = n;
  }

  u16* Arow = Asm + lane*TK;
  const u16* Awave = Asm;

  float sigma = 0.f;
  f32x4 acc[4][2];
  #pragma unroll
  for (int t = 0; t < 4; t++){
    acc[t][0] = (f32x4){0.f,0.f,0.f,0.f};
    acc[t][1] = (f32x4){0.f,0.f,0.f,0.f};
  }

  uint4 z4 = make_uint4(0,0,0,0);
  *(uint4*)(Arow + 48) = z4;
  *(uint4*)(Arow + 56) = z4;

  #pragma unroll 1
  for (int p = 0; p < 3; p++){
    const float dc = (p==0) ? Z : ((p==1) ? Y : X);
    const float hc = (p==0) ? Y : Z;

    uint4 b00 = Bfr[(p*4 + 0)*64 + lane];
    uint4 b01 = Bfr[(p*4 + 1)*64 + lane];
    uint4 b10 = Bfr[(p*4 + 2)*64 + lane];
    uint4 b11 = Bfr[(p*4 + 3)*64 + lane];

    IdxW D = idxw(dc), H = idxw(hc);
    const float fd = D.f, fh = H.f;
    const float w00 = (1.f-fd)*(1.f-fh), w01 = (1.f-fd)*fh;
    const float w10 = fd*(1.f-fh),       w11 = fd*fh;

    { // density -> sigma via V-table: 4 x 8B loads
      uint2 v00 = Vt[(p*GG+D.i0)*GG+H.i0];
      uint2 v01 = Vt[(p*GG+D.i0)*GG+H.i1];
      uint2 v10 = Vt[(p*GG+D.i1)*GG+H.i0];
      uint2 v11 = Vt[(p*GG+D.i1)*GG+H.i1];
      // corner (d0,hi): (1-fd)*V0 + fd*Vp ; corner (d1,hi): (1-fd)*Vm + fd*V0
      float s00 = (1.f-fd)*bflo(v00.x) + fd*bfhi(v00.x);
      float s01 = (1.f-fd)*bflo(v01.x) + fd*bfhi(v01.x);
      float s10 = (1.f-fd)*bflo(v10.y) + fd*bflo(v10.x);
      float s11 = (1.f-fd)*bflo(v11.y) + fd*bflo(v11.x);
      sigma += (1.f-fh)*((1.f-fd)*s00 + fd*s10) + fh*((1.f-fd)*s01 + fd*s11);
    }

    { // app feats: fp8 corners + fp8 lines -> LDS A tile (bf16)
      const u8* C00 = apt + ((size_t)((p*GG+D.i0)*GG+H.i0))*48;
      const u8* C01 = apt + ((size_t)((p*GG+D.i0)*GG+H.i1))*48;
      const u8* C10 = apt + ((size_t)((p*GG+D.i1)*GG+H.i0))*48;
      const u8* C11 = apt + ((size_t)((p*GG+D.i1)*GG+H.i1))*48;
      const u8* L0  = alt + (size_t)(p*GG+D.i0)*48;
      const u8* L1  = alt + (size_t)(p*GG+D.i1)*48;
      #pragma unroll 1
      for (int g = 0; g < 3; g++){
        uint4 q00 = *(const uint4*)(C00 + g*16);   // 16 fp8 channels
        uint4 q01 = *(const uint4*)(C01 + g*16);
        uint4 q10 = *(const uint4*)(C10 + g*16);
        uint4 q11 = *(const uint4*)(C11 + g*16);
        uint4 lq0 = *(const uint4*)(L0 + g*16);
        uint4 lq1 = *(const uint4*)(L1 + g*16);
        u32 a00[4]={q00.x,q00.y,q00.z,q00.w};
        u32 a01[4]={q01.x,q01.y,q01.z,q01.w};
        u32 a10[4]={q10.x,q10.y,q10.z,q10.w};
        u32 a11[4]={q11.x,q11.y,q11.z,q11.w};
        u32 l0w[4]={lq0.x,lq0.y,lq0.z,lq0.w};
        u32 l1w[4]={lq1.x,lq1.y,lq1.z,lq1.w};
        float ft[16];
        #pragma unroll
        for (int w = 0; w < 4; w++){
          f32x2 p00a = __builtin_amdgcn_cvt_pk_f32_fp8((int)a00[w], false);
          f32x2 p00b = __builtin_amdgcn_cvt_pk_f32_fp8((int)a00[w], true);
          f32x2 p01a = __builtin_amdgcn_cvt_pk_f32_fp8((int)a01[w], false);
          f32x2 p01b = __builtin_amdgcn_cvt_pk_f32_fp8((int)a01[w], true);
          f32x2 p10a = __builtin_amdgcn_cvt_pk_f32_fp8((int)a10[w], false);
          f32x2 p10b = __builtin_amdgcn_cvt_pk_f32_fp8((int)a10[w], true);
          f32x2 p11a = __builtin_amdgcn_cvt_pk_f32_fp8((int)a11[w], false);
          f32x2 p11b = __builtin_amdgcn_cvt_pk_f32_fp8((int)a11[w], true);
          f32x2 q0a  = __builtin_amdgcn_cvt_pk_f32_fp8((int)l0w[w], false);
          f32x2 q0b  = __builtin_amdgcn_cvt_pk_f32_fp8((int)l0w[w], true);
          f32x2 q1a  = __builtin_amdgcn_cvt_pk_f32_fp8((int)l1w[w], false);
          f32x2 q1b  = __builtin_amdgcn_cvt_pk_f32_fp8((int)l1w[w], true);
          float pv0 = w00*p00a.x + w01*p01a.x + w10*p10a.x + w11*p11a.x;
          float pv1 = w00*p00a.y + w01*p01a.y + w10*p10a.y + w11*p11a.y;
          float pv2 = w00*p00b.x + w01*p01b.x + w10*p10b.x + w11*p11b.x;
          float pv3 = w00*p00b.y + w01*p01b.y + w10*p10b.y + w11*p11b.y;
          ft[4*w+0] = pv0 * (q0a.x + fd*(q1a.x - q0a.x));
          ft[4*w+1] = pv1 * (q0a.y + fd*(q1a.y - q0a.y));
          ft[4*w+2] = pv2 * (q0b.x + fd*(q1b.x - q0b.x));
          ft[4*w+3] = pv3 * (q0b.y + fd*(q1b.y - q0b.y));
        }
        uint4 d0, d1;
        d0.x=(u32)f2bf(ft[0])|((u32)f2bf(ft[1])<<16);
        d0.y=(u32)f2bf(ft[2])|((u32)f2bf(ft[3])<<16);
        d0.z=(u32)f2bf(ft[4])|((u32)f2bf(ft[5])<<16);
        d0.w=(u32)f2bf(ft[6])|((u32)f2bf(ft[7])<<16);
        d1.x=(u32)f2bf(ft[8])|((u32)f2bf(ft[9])<<16);
        d1.y=(u32)f2bf(ft[10])|((u32)f2bf(ft[11])<<16);
        d1.z=(u32)f2bf(ft[12])|((u32)f2bf(ft[13])<<16);
        d1.w=(u32)f2bf(ft[14])|((u32)f2bf(ft[15])<<16);
        *(uint4*)(Arow + g*16)     = d0;
        *(uint4*)(Arow + g*16 + 8) = d1;
      }
    }

    // compiler-only fence: LDS ops within a wave complete in order in HW.
    asm volatile("" ::: "memory");

    #pragma unroll
    for (int t = 0; t < 4; t++){
      const u16* ab = Awave + (t*16 + (lane & 15))*TK + ((lane >> 4) * 8);
      s16x8 a0 = __builtin_bit_cast(s16x8, *(const uint4*)ab);
      s16x8 a1 = __builtin_bit_cast(s16x8, *(const uint4*)(ab + 32));
      acc[t][0] = __builtin_amdgcn_mfma_f32_16x16x32_bf16(a0, __builtin_bit_cast(s16x8,b00), acc[t][0], 0,0,0);
      acc[t][0] = __builtin_amdgcn_mfma_f32_16x16x32_bf16(a1, __builtin_bit_cast(s16x8,b01), acc[t][0], 0,0,0);
      acc[t][1] = __builtin_amdgcn_mfma_f32_16x16x32_bf16(a0, __builtin_bit_cast(s16x8,b10), acc[t][1], 0,0,0);
      acc[t][1] = __builtin_amdgcn_mfma_f32_16x16x32_bf16(a1, __builtin_bit_cast(s16x8,b11), acc[t][1], 0,0,0);
    }
    asm volatile("" ::: "memory");   // keep next plane's LDS writes below these reads
  }

  outv[pn] = sigma;

  float* ao = outv + NPTS;
  #pragma unroll
  for (int t = 0; t < 4; t++){
    #pragma unroll
    for (int nt = 0; nt < 2; nt++){
      int a = nt*16 + (lane & 15);
      #pragma unroll
      for (int r = 0; r < 4; r++){
        int src = t*16 + (lane >> 4)*4 + r;
        int pr = __shfl(pn, src);
        if (a < ADIM)
          ao[(size_t)pr*ADIM + a] = acc[t][nt][r];
      }
    }
  }
}

// ---- fallback: direct fp32 sampling ----
__global__ void sample_naive(const float* __restrict__ xyz,
    const float* __restrict__ dp, const float* __restrict__ dl,
    const float* __restrict__ ap, const float* __restrict__ al,
    const float* __restrict__ W,  float* __restrict__ outv)
{
  int n = blockIdx.x*blockDim.x + threadIdx.x;
  if (n >= NPTS) return;
  float X = xyz[3*n], Y = xyz[3*n+1], Z = xyz[3*n+2];
  float dco[3] = {Z, Y, X};
  float hco[3] = {Y, Z, Z};
  float sigma = 0.f, acc[ADIM];
  for (int a = 0; a < ADIM; a++) acc[a] = 0.f;
  for (int p = 0; p < 3; p++){
    IdxW D = idxw(dco[p]), H = idxw(hco[p]);
    float fd = D.f, fh = H.f;
    float w00=(1.f-fd)*(1.f-fh), w01=(1.f-fd)*fh, w10=fd*(1.f-fh), w11=fd*fh;
    for (int c = 0; c < CDEN; c++){
      const float* pl = dp + (size_t)(p*CDEN + c)*GG*GG;
      float pv = w00*pl[D.i0*GG+H.i0] + w01*pl[D.i0*GG+H.i1]
               + w10*pl[D.i1*GG+H.i0] + w11*pl[D.i1*GG+H.i1];
      const float* ll = dl + (p*CDEN + c)*GG;
      sigma += pv * (ll[D.i0] + fd*(ll[D.i1] - ll[D.i0]));
    }
    for (int c = 0; c < CAPP; c++){
      const float* pl = ap + (size_t)(p*CAPP + c)*GG*GG;
      float pv = w00*pl[D.i0*GG+H.i0] + w01*pl[D.i0*GG+H.i1]
               + w10*pl[D.i1*GG+H.i0] + w11*pl[D.i1*GG+H.i1];
      const float* ll = al + (p*CAPP + c)*GG;
      float ft = pv * (ll[D.i0] + fd*(ll[D.i1] - ll[D.i0]));
      int k = p*CAPP + c;
      for (int a = 0; a < ADIM; a++) acc[a] = fmaf(ft, W[a*KTOT + k], acc[a]);
    }
  }
  outv[n] = sigma;
  for (int a = 0; a < ADIM; a++) outv[NPTS + (size_t)n*ADIM + a] = acc[a];
}

extern "C" void kernel_launch(void* const* d_in, const int* in_sizes, int n_in,
                              void* d_out, int out_size, void* d_ws, size_t ws_size,
                              hipStream_t stream){
  const float* xyz    = (const float*)d_in[0];
  const float* dplane = (const float*)d_in[1];
  const float* dline  = (const float*)d_in[2];
  const float* aplane = (const float*)d_in[3];
  const float* aline  = (const float*)d_in[4];
  const float* W      = (const float*)d_in[5];
  float* outv = (float*)d_out;

  const size_t sz_vt   = (size_t)3*GG*GG*8;       // 2,160,000
  const size_t sz_apt  = (size_t)3*GG*GG*48;      // fp8: 12,960,000
  const size_t sz_alt  = (size_t)3*GG*48;
  const size_t sz_bfr  = (size_t)3*2*2*64*16;
  const size_t sz_hist = (size_t)NBUCK_PAD*4;
  const size_t sz_offs = (size_t)NBUCK_PAD*4;
  const size_t sz_csum = (size_t)NCHUNK*4;
  const size_t sz_keys = (size_t)NPTS*4;
  const size_t sz_xyzq = (size_t)NPTS*16;

  const size_t off_apt  = sz_vt;
  const size_t off_alt  = off_apt + sz_apt;
  const size_t off_bfr  = off_alt + sz_alt;
  const size_t off_hist = off_bfr + sz_bfr;
  const size_t off_offs = off_hist + sz_hist;
  const size_t off_csum = off_offs + sz_offs;
  const size_t off_keys = off_csum + sz_csum;
  const size_t off_xyzq = off_keys + sz_keys;
  const size_t need_tab  = off_hist;
  const size_t need_full = off_xyzq + sz_xyzq;

  if (ws_size < need_tab){
    sample_naive<<<(NPTS+255)/256, 256, 0, stream>>>(xyz, dplane, dline, aplane, aline, W, outv);
    return;
  }

  uint2* vt  = (uint2*)((char*)d_ws);
  u8*    apt = (u8*)((char*)d_ws + off_apt);
  u8*    alt = (u8*)((char*)d_ws + off_alt);
  uint4* bfr = (uint4*)((char*)d_ws + off_bfr);

  if (ws_size < need_full){
    prep_all<<<2*TPBLK + 7, 256, 0, stream>>>(dplane, aplane, dline, aline, W, xyz,
                                              vt, apt, alt, bfr, nullptr, nullptr);
    sample_mfma<false><<<NBLK64, 64, 0, stream>>>(nullptr, xyz, vt, apt, alt, bfr, outv);
    return;
  }

  u32*    hist = (u32*)((char*)d_ws + off_hist);
  u32*    offs = (u32*)((char*)d_ws + off_offs);
  u32*    csum = (u32*)((char*)d_ws + off_csum);
  u32*    keys = (u32*)((char*)d_ws + off_keys);
  float4* xyzq = (float4*)((char*)d_ws + off_xyzq);

  hipMemsetAsync(hist, 0, sz_hist, stream);
  prep_all<<<2*TPBLK + 7 + NBLK, 256, 0, stream>>>(dplane, aplane, dline, aline, W, xyz,
                                                   vt, apt, alt, bfr, hist, keys);
  scan1<<<NCHUNK, 1024, 0, stream>>>(hist, offs, csum);
  scatter_pts<<<NBLK, 256, 0, stream>>>(xyz, keys, offs, csum, xyzq);
  sample_mfma<true><<<NBLK64, 64, 0, stream>>>(xyzq, nullptr, vt, apt, alt, bfr, outv);
}